// Round 1
// baseline (6284.176 us; speedup 1.0000x reference)
//
#include <hip/hip_runtime.h>
#include <hip/hip_bf16.h>

// ============================================================================
// CategoricalGraphAtt on MI355X.
// Pipeline: [f2bf preps] -> persistent GRU (4 batch-groups x 64 j-slice WGs,
// fused x-projection, B in VGPRs, cross-WG flag barrier) -> fused time-attention
// (GEMM+softmax+weighted sum per 64-column block) -> small fp32 GEMMs + GAT
// attention + pooling + fusion + heads.
// ============================================================================

typedef __bf16 bf16x8 __attribute__((ext_vector_type(8)));
typedef float  floatx4 __attribute__((ext_vector_type(4)));

struct US8 { unsigned short u[8]; };

__device__ __forceinline__ unsigned short f2bf(float f) {
  unsigned u = __builtin_bit_cast(unsigned, f);
  u += 0x7fffu + ((u >> 16) & 1u);           // RNE
  return (unsigned short)(u >> 16);
}
__device__ __forceinline__ float bf2f(unsigned short h) {
  return __builtin_bit_cast(float, ((unsigned)h) << 16);
}
__device__ __forceinline__ float sigm(float x) { return 1.f / (1.f + __expf(-x)); }

// ---------------- workspace layout (bytes) ----------------
static const size_t OF_XBF   = 0;                 // bf16 x [100][512][256]   26,214,400
static const size_t OF_HIST  = 26214400;          // bf16 h_hist [513][100][1024] 105,062,400
static const size_t OF_FLAGS = 131276800;         // int [256] (+pad)         1,024
static const size_t OF_ENCW  = 131277824;         // bf16 enc_att_W [512][512] 524,288
static const size_t OF_V     = 131802112;         // f32 v [100][1024]
static const size_t OF_HIN   = 132211712;         // f32 inner-GAT h
static const size_t OF_IEMB  = 132621312;         // f32 inner_emb
static const size_t OF_CATV  = 133030912;         // f32 cat_vec (pooled) [5][1024]
static const size_t OF_CATH  = 133051392;         // f32 cat-GAT h
static const size_t OF_CATO  = 133071872;         // f32 cat GAT out
static const size_t OF_FBUF  = 133092352;         // f32 fusion input [100][3072]
static const size_t OF_FOUT  = 134321152;         // f32 fusion output [100][1024]

// ---------------- fp32 -> bf16 convert ----------------
__global__ void f2bf_kernel(const float* __restrict__ src, unsigned short* __restrict__ dst, int n4) {
  int i = blockIdx.x * 256 + threadIdx.x;
  if (i < n4) {
    float4 v = ((const float4*)src)[i];
    ushort4 o;
    o.x = f2bf(v.x); o.y = f2bf(v.y); o.z = f2bf(v.z); o.w = f2bf(v.w);
    ((ushort4*)dst)[i] = o;
  }
}

// ---------------- persistent GRU recurrence ----------------
// grid 256 = 4 groups(25 rows) x 64 slices(16 j). block 320 (5 waves).
// waves 0-3: k-steps 8w..8w+8 of h-part (K=1024); wave 4: x-part (K=256).
// LDS: Bw gather scratch 122880 | bias 256 @122880 | ghp [5][2][3][256] f32 @123136 | hfp [400] f32 @153856
#define GRU_LDS 155456
__global__ void __launch_bounds__(320) gru_recur(
    const unsigned short* __restrict__ xbf,
    const float* __restrict__ Whh, const float* __restrict__ Wih,
    const float* __restrict__ bih, const float* __restrict__ bhh,
    unsigned short* hist, int* flags)
{
  extern __shared__ char smem[];
  unsigned short* Bw  = (unsigned short*)smem;       // 61440 bf16 frags
  float* biasl = (float*)(smem + 122880);            // [4][16]: r,z,hn,xn
  float* ghp   = (float*)(smem + 123136);            // [5][2][3][16col][16row]
  float* hfp   = (float*)(smem + 153856);            // fp32 h state [25][16]

  const int tid  = threadIdx.x;
  const int lane = tid & 63;
  const int w    = tid >> 6;       // 0..4
  const int wg   = blockIdx.x;
  const int g    = wg >> 6;        // batch group 0..3
  const int s    = wg & 63;        // j slice 0..63
  const int gb   = g * 25;

  // ---- gather B (Whh/Wih rows for this slice) into LDS in frag order ----
  // octets: Brz [2][40][64] | Bnh [32][64] @5120 | Bnx [8][64] @7168
  for (int o = tid; o < 7680; o += 320) {
    int kk, ln; const float* sp; unsigned short* dst;
    if (o < 5120) {
      int q = o >= 2560; int rem = o - q * 2560;
      kk = rem >> 6; ln = rem & 63;
      int l = ln & 15, ksub = ln >> 4, j = s * 16 + l;
      int k = kk * 32 + ksub * 8;
      sp = (k < 1024) ? (Whh + (size_t)(q * 1024 + j) * 1024 + k)
                      : (Wih + (size_t)(q * 1024 + j) * 256 + (k - 1024));
      dst = Bw + ((size_t)((q * 40 + kk) * 64 + ln)) * 8;
    } else if (o < 7168) {
      int o2 = o - 5120; kk = o2 >> 6; ln = o2 & 63;
      int l = ln & 15, ksub = ln >> 4, j = s * 16 + l;
      sp = Whh + (size_t)(2048 + j) * 1024 + kk * 32 + ksub * 8;
      dst = Bw + (size_t)(5120 + kk * 64 + ln) * 8;
    } else {
      int o3 = o - 7168; kk = o3 >> 6; ln = o3 & 63;
      int l = ln & 15, ksub = ln >> 4, j = s * 16 + l;
      sp = Wih + (size_t)(2048 + j) * 256 + kk * 32 + ksub * 8;
      dst = Bw + (size_t)(7168 + kk * 64 + ln) * 8;
    }
    float4 f0 = *(const float4*)sp;
    float4 f1 = *(const float4*)(sp + 4);
    dst[0] = f2bf(f0.x); dst[1] = f2bf(f0.y); dst[2] = f2bf(f0.z); dst[3] = f2bf(f0.w);
    dst[4] = f2bf(f1.x); dst[5] = f2bf(f1.y); dst[6] = f2bf(f1.z); dst[7] = f2bf(f1.w);
  }
  if (tid < 16) {
    int j = s * 16 + tid;
    biasl[tid]      = bih[j]        + bhh[j];
    biasl[16 + tid] = bih[1024 + j] + bhh[1024 + j];
    biasl[32 + tid] = bhh[2048 + j];
    biasl[48 + tid] = bih[2048 + j];
  }
  for (int i = tid; i < 400; i += 320) hfp[i] = 0.f;
  __syncthreads();

  // ---- hoist B fragments into registers (persist across all 512 steps) ----
  bf16x8 Breg[24];
  #pragma unroll
  for (int lk = 0; lk < 8; lk++) {
    int kk = w * 8 + lk;
    Breg[lk * 3 + 0] = __builtin_bit_cast(bf16x8, *(const int4*)(Bw + (size_t)((kk)      * 64 + lane) * 8));
    Breg[lk * 3 + 1] = __builtin_bit_cast(bf16x8, *(const int4*)(Bw + (size_t)((40 + kk) * 64 + lane) * 8));
    const unsigned short* np = (w < 4)
        ? (Bw + (size_t)(5120 + kk * 64 + lane) * 8)
        : (Bw + (size_t)(7168 + (kk - 32) * 64 + lane) * 8);
    Breg[lk * 3 + 2] = __builtin_bit_cast(bf16x8, *(const int4*)np);
  }

  const int kfrag = (lane >> 4) * 8;
  size_t rowh[2], rowx[2];
  #pragma unroll
  for (int mt = 0; mt < 2; mt++) {
    int m = mt * 16 + (lane & 15);
    int bb = (m < 25) ? m : 24;           // clamp pad rows
    rowh[mt] = (size_t)(gb + bb) * 1024;
    rowx[mt] = (size_t)(gb + bb) * 512 * 256;
  }

  for (int t = 0; t < 512; t++) {
    const unsigned short* hrow = hist + (size_t)t * 102400;
    floatx4 acc[2][3];
    #pragma unroll
    for (int mt = 0; mt < 2; mt++)
      #pragma unroll
      for (int gg = 0; gg < 3; gg++) acc[mt][gg] = floatx4{0.f, 0.f, 0.f, 0.f};

    #pragma unroll
    for (int lk = 0; lk < 8; lk++) {
      int kk = w * 8 + lk;
      #pragma unroll
      for (int mt = 0; mt < 2; mt++) {
        const unsigned short* ap = (w < 4)
            ? (hrow + rowh[mt] + kk * 32 + kfrag)
            : (xbf + rowx[mt] + (size_t)t * 256 + (kk - 32) * 32 + kfrag);
        bf16x8 a = __builtin_bit_cast(bf16x8, *(const int4*)ap);
        acc[mt][0] = __builtin_amdgcn_mfma_f32_16x16x32_bf16(a, Breg[lk * 3 + 0], acc[mt][0], 0, 0, 0);
        acc[mt][1] = __builtin_amdgcn_mfma_f32_16x16x32_bf16(a, Breg[lk * 3 + 1], acc[mt][1], 0, 0, 0);
        acc[mt][2] = __builtin_amdgcn_mfma_f32_16x16x32_bf16(a, Breg[lk * 3 + 2], acc[mt][2], 0, 0, 0);
      }
    }

    // partials -> LDS ([col][row] so float4 is contiguous)
    int colrow = (lane & 15) * 16 + (lane >> 4) * 4;
    #pragma unroll
    for (int mt = 0; mt < 2; mt++)
      #pragma unroll
      for (int gg = 0; gg < 3; gg++)
        *(floatx4*)(ghp + (size_t)((w * 2 + mt) * 3 + gg) * 256 + colrow) = acc[mt][gg];
    __syncthreads();

    // epilogue: 200 items = 25 rows x 8 l-pairs
    if (tid < 200) {
      int b2 = tid >> 3, lp = tid & 7, l0 = lp * 2;
      int mt2 = b2 >> 4, rr = b2 & 15;
      unsigned packed = 0;
      #pragma unroll
      for (int ii = 0; ii < 2; ii++) {
        int l = l0 + ii;
        float ghr = 0, ghz = 0, ghnh = 0, ghnx = 0;
        #pragma unroll
        for (int ww = 0; ww < 4; ww++) {
          const float* gq = ghp + (size_t)((ww * 2 + mt2) * 3) * 256 + l * 16 + rr;
          ghr += gq[0]; ghz += gq[256]; ghnh += gq[512];
        }
        { const float* gq = ghp + (size_t)((4 * 2 + mt2) * 3) * 256 + l * 16 + rr;
          ghr += gq[0]; ghz += gq[256]; ghnx = gq[512]; }
        float r = sigm(ghr + biasl[l]);
        float z = sigm(ghz + biasl[16 + l]);
        float nv = ghnx + biasl[48 + l] + r * (ghnh + biasl[32 + l]);
        nv = fminf(fmaxf(nv, -15.f), 15.f);
        float e2 = __expf(-2.f * nv);
        float n = (1.f - e2) / (1.f + e2);
        float ho = hfp[b2 * 16 + l];
        float hn = (1.f - z) * n + z * ho;
        hfp[b2 * 16 + l] = hn;
        packed |= ((unsigned)f2bf(hn)) << (16 * ii);
      }
      // agent-scope (LLC-visible) store: other XCDs read this next step
      __hip_atomic_store(
          (unsigned*)(hist + (size_t)(t + 1) * 102400 + (size_t)(gb + b2) * 1024 + s * 16 + l0),
          packed, __ATOMIC_RELAXED, __HIP_MEMORY_SCOPE_AGENT);
    }
    __syncthreads();   // drains vmcnt: all h' stores complete (at LLC) before flag

    if (t < 511) {
      if (tid == 0)
        __hip_atomic_store(flags + wg, t + 1, __ATOMIC_RELEASE, __HIP_MEMORY_SCOPE_AGENT);
      if (w == 0) {
        for (;;) {
          int vf = __hip_atomic_load(flags + g * 64 + lane, __ATOMIC_RELAXED, __HIP_MEMORY_SCOPE_AGENT);
          if (__all(vf >= t + 1)) break;
          __builtin_amdgcn_s_sleep(1);
        }
      }
      __syncthreads();
      asm volatile("" ::: "memory");   // no hoisting of next step's loads above the spin
    }
  }
}

// ---------------- fused time attention ----------------
// grid 1600 (one 64-col block of n'=(b*1024+d)), block 512 (8 waves).
// w[u,n] = sum_t encW[u,t]*hs[t,n] + bt[u]; softmax over u; v[n] = sum p*hs[u,n].
#define ATT_LDS 68096
__global__ void __launch_bounds__(512) att_pool(
    const unsigned short* __restrict__ hist,   // slots 1..512
    const unsigned short* __restrict__ encw,   // bf16 [512][512]
    const float* __restrict__ encb,
    float* __restrict__ vout)
{
  extern __shared__ char smem[];
  unsigned short* Bs = (unsigned short*)smem;          // [16ks][4nt][64lane][8]
  float* red  = (float*)(smem + 65536);                // [8][64]
  float* cmax = (float*)(smem + 65536 + 2048);
  float* csum = (float*)(smem + 65536 + 2048 + 256);

  const int tid = threadIdx.x, w = tid >> 6, lane = tid & 63;
  const int q = lane >> 4, col = lane & 15;
  const int n0 = blockIdx.x * 64;
  const int bg = n0 >> 10, d0 = n0 & 1023;

  // stage hs tile (coalesced [t][d] reads, transposed scatter into frag layout)
  for (int ii = 0; ii < 8; ii++) {
    int c = tid + 512 * ii;
    int t = c >> 3, dd = c & 7;
    int4 li = *(const int4*)(hist + (size_t)(t + 1) * 102400 + (size_t)bg * 1024 + d0 + dd * 8);
    US8 u8 = __builtin_bit_cast(US8, li);
    int kstep = t >> 5, ksub = (t >> 3) & 3, i = t & 7;
    int ntile = dd >> 1, nc0 = (dd & 1) * 8;
    unsigned short* dst = Bs + ((size_t)((kstep * 4 + ntile) * 64 + ksub * 16 + nc0)) * 8 + i;
    #pragma unroll
    for (int jj = 0; jj < 8; jj++) dst[jj * 8] = u8.u[jj];
  }
  __syncthreads();

  floatx4 acc[4][4];
  #pragma unroll
  for (int mi = 0; mi < 4; mi++)
    #pragma unroll
    for (int ni = 0; ni < 4; ni++) acc[mi][ni] = floatx4{0.f, 0.f, 0.f, 0.f};

  #pragma unroll 2
  for (int kk = 0; kk < 16; kk++) {
    int tch = kk * 32 + q * 8;
    bf16x8 af[4];
    #pragma unroll
    for (int mi = 0; mi < 4; mi++) {
      int u = (w * 4 + mi) * 16 + col;
      af[mi] = __builtin_bit_cast(bf16x8, *(const int4*)(encw + (size_t)u * 512 + tch));
    }
    #pragma unroll
    for (int ni = 0; ni < 4; ni++) {
      bf16x8 bf = __builtin_bit_cast(bf16x8, *(const int4*)(Bs + (size_t)((kk * 4 + ni) * 64 + lane) * 8));
      #pragma unroll
      for (int mi = 0; mi < 4; mi++)
        acc[mi][ni] = __builtin_amdgcn_mfma_f32_16x16x32_bf16(af[mi], bf, acc[mi][ni], 0, 0, 0);
    }
  }

  // + row bias
  #pragma unroll
  for (int mi = 0; mi < 4; mi++) {
    int ub = (w * 4 + mi) * 16 + q * 4;
    float b0 = encb[ub], b1 = encb[ub + 1], b2 = encb[ub + 2], b3 = encb[ub + 3];
    #pragma unroll
    for (int ni = 0; ni < 4; ni++) {
      acc[mi][ni][0] += b0; acc[mi][ni][1] += b1; acc[mi][ni][2] += b2; acc[mi][ni][3] += b3;
    }
  }
  // column max
  #pragma unroll
  for (int ni = 0; ni < 4; ni++) {
    float m = -1e30f;
    #pragma unroll
    for (int mi = 0; mi < 4; mi++)
      #pragma unroll
      for (int r = 0; r < 4; r++) m = fmaxf(m, acc[mi][ni][r]);
    m = fmaxf(m, __shfl_xor(m, 16)); m = fmaxf(m, __shfl_xor(m, 32));
    red[w * 64 + ni * 16 + col] = m;
  }
  __syncthreads();
  if (tid < 64) {
    float m = red[tid];
    for (int w2 = 1; w2 < 8; w2++) m = fmaxf(m, red[w2 * 64 + tid]);
    cmax[tid] = m;
  }
  __syncthreads();
  // exp + column sum
  #pragma unroll
  for (int ni = 0; ni < 4; ni++) {
    float cm = cmax[ni * 16 + col];
    float sum = 0.f;
    #pragma unroll
    for (int mi = 0; mi < 4; mi++)
      #pragma unroll
      for (int r = 0; r < 4; r++) {
        float e = __expf(acc[mi][ni][r] - cm);
        acc[mi][ni][r] = e; sum += e;
      }
    sum += __shfl_xor(sum, 16); sum += __shfl_xor(sum, 32);
    red[w * 64 + ni * 16 + col] = sum;
  }
  __syncthreads();
  if (tid < 64) {
    float sm = 0.f;
    for (int w2 = 0; w2 < 8; w2++) sm += red[w2 * 64 + tid];
    csum[tid] = sm;
  }
  __syncthreads();
  // weighted sum of hs
  #pragma unroll
  for (int ni = 0; ni < 4; ni++) {
    float p = 0.f;
    #pragma unroll
    for (int mi = 0; mi < 4; mi++) {
      int u0 = (w * 4 + mi) * 16 + q * 4;
      int ks = u0 >> 5, ksb = (u0 >> 3) & 3, i0 = u0 & 7;
      const unsigned short* hp = Bs + (size_t)((ks * 4 + ni) * 64 + ksb * 16 + col) * 8 + i0;
      p += acc[mi][ni][0] * bf2f(hp[0]) + acc[mi][ni][1] * bf2f(hp[1])
         + acc[mi][ni][2] * bf2f(hp[2]) + acc[mi][ni][3] * bf2f(hp[3]);
    }
    p += __shfl_xor(p, 16); p += __shfl_xor(p, 32);
    red[w * 64 + ni * 16 + col] = p;
  }
  __syncthreads();
  if (tid < 64) {
    float p = 0.f;
    for (int w2 = 0; w2 < 8; w2++) p += red[w2 * 64 + tid];
    vout[n0 + tid] = p / csum[tid];
  }
}

// ---------------- small fp32 GEMM: C(M,N) = A(M,K) @ B(N,K)^T [+bias][+relu] ----------------
__global__ void gemm_bt(const float* __restrict__ A, const float* __restrict__ B,
                        float* __restrict__ C, int M, int N, int K,
                        const float* __restrict__ bias, int relu)
{
  __shared__ float Al[16][33];
  __shared__ float Bl[64][33];
  int tx = threadIdx.x;
  int nb = blockIdx.x, mb = blockIdx.y;
  int n = nb * 64 + (tx & 63);
  int mq = tx >> 6;
  float acc[4] = {0.f, 0.f, 0.f, 0.f};
  for (int k0 = 0; k0 < K; k0 += 32) {
    for (int e = tx; e < 512; e += 256) {
      int r = e >> 5, c = e & 31; int m = mb * 16 + r;
      Al[r][c] = (m < M) ? A[(size_t)m * K + k0 + c] : 0.f;
    }
    for (int e = tx; e < 2048; e += 256) {
      int r = e >> 5, c = e & 31;
      Bl[r][c] = B[(size_t)(nb * 64 + r) * K + k0 + c];
    }
    __syncthreads();
    int nn = tx & 63;
    #pragma unroll 8
    for (int c = 0; c < 32; c++) {
      float bv = Bl[nn][c];
      #pragma unroll
      for (int i = 0; i < 4; i++) acc[i] += Al[mq * 4 + i][c] * bv;
    }
    __syncthreads();
  }
  #pragma unroll
  for (int i = 0; i < 4; i++) {
    int m = mb * 16 + mq * 4 + i;
    if (m < M && n < N) {
      float r = acc[i] + (bias ? bias[n] : 0.f);
      if (relu) r = fmaxf(r, 0.f);
      C[(size_t)m * N + n] = r;
    }
  }
}

// ---------------- GAT attention (complete graph + self loops within each block of NN nodes) ----------------
template <int NN>
__global__ void gat_att(const float* __restrict__ h, const float* __restrict__ asrc,
                        const float* __restrict__ adst, const float* __restrict__ bias,
                        float* __restrict__ out)
{
  __shared__ float asd[2][NN];
  __shared__ float P[NN][NN];
  int c = blockIdx.x, tx = threadIdx.x;
  int wid = tx >> 6, lane = tx & 63;
  for (int idx = wid; idx < 2 * NN; idx += 4) {
    int which = idx >= NN; int j = which ? idx - NN : idx;
    const float* av = which ? adst : asrc;
    float p = 0.f;
    for (int k = lane; k < 1024; k += 64) p += h[(size_t)(c * NN + j) * 1024 + k] * av[k];
    for (int m = 32; m; m >>= 1) p += __shfl_xor(p, m);
    if (lane == 0) asd[which][j] = p;
  }
  __syncthreads();
  if (tx < NN) {
    int i = tx; float mx = -1e30f; float e[NN];
    #pragma unroll
    for (int j = 0; j < NN; j++) {
      float x = asd[0][j] + asd[1][i];
      x = (x < 0.f) ? 0.2f * x : x;
      e[j] = x; mx = fmaxf(mx, x);
    }
    float s = 0.f;
    #pragma unroll
    for (int j = 0; j < NN; j++) { e[j] = __expf(e[j] - mx); s += e[j]; }
    #pragma unroll
    for (int j = 0; j < NN; j++) P[i][j] = e[j] / s;
  }
  __syncthreads();
  for (int ee = tx; ee < NN * 1024; ee += 256) {
    int i = ee >> 10, d = ee & 1023;
    float s = 0.f;
    #pragma unroll
    for (int j = 0; j < NN; j++) s += P[i][j] * h[(size_t)(c * NN + j) * 1024 + d];
    out[(size_t)(c * NN + i) * 1024 + d] = s + bias[d];
  }
}

// ---------------- stock->category pooling attention ----------------
__global__ void pool_att(const float* __restrict__ v, const float* __restrict__ pW,
                         const float* __restrict__ pb, float* __restrict__ catv)
{
  __shared__ float W[400]; __shared__ float bsh[20];
  int tx = threadIdx.x;
  for (int i = tx; i < 400; i += 256) W[i] = pW[i];
  if (tx < 20) bsh[tx] = pb[tx];
  __syncthreads();
  int gid = blockIdx.x * 256 + tx;
  int c = gid >> 10, d = gid & 1023;
  float vals[20];
  #pragma unroll
  for (int t = 0; t < 20; t++) vals[t] = v[(size_t)(c * 20 + t) * 1024 + d];
  float wv[20]; float mx = -1e30f;
  #pragma unroll
  for (int u = 0; u < 20; u++) {
    float s = bsh[u];
    #pragma unroll
    for (int t = 0; t < 20; t++) s += vals[t] * W[u * 20 + t];
    wv[u] = s; mx = fmaxf(mx, s);
  }
  float sum = 0.f, out = 0.f;
  #pragma unroll
  for (int u = 0; u < 20; u++) { float e = __expf(wv[u] - mx); sum += e; out += e * vals[u]; }
  catv[gid] = out / sum;
}

// ---------------- fusion concat ----------------
__global__ void concat_kernel(const float* __restrict__ v, const float* __restrict__ cato,
                              const float* __restrict__ iemb, float* __restrict__ F)
{
  int gid = blockIdx.x * 256 + threadIdx.x;
  if (gid < 307200) {
    int i = gid / 3072;
    int k = gid - i * 3072;
    float r;
    if (k < 1024)       r = v[(size_t)i * 1024 + k];
    else if (k < 2048)  r = cato[(size_t)(i / 20) * 1024 + (k - 1024)];
    else                r = iemb[(size_t)i * 1024 + (k - 2048)];
    F[gid] = r;
  }
}

// ---------------- output heads ----------------
__global__ void heads(const float* __restrict__ f, const float* __restrict__ rw,
                      const float* __restrict__ rb, const float* __restrict__ cw,
                      const float* __restrict__ cb, float* __restrict__ out)
{
  int b = blockIdx.x * 4 + (threadIdx.x >> 6);
  int lane = threadIdx.x & 63;
  float pr = 0.f, pc = 0.f;
  for (int k = lane; k < 1024; k += 64) {
    float x = f[(size_t)b * 1024 + k];
    pr += x * rw[k]; pc += x * cw[k];
  }
  for (int m = 32; m; m >>= 1) { pr += __shfl_xor(pr, m); pc += __shfl_xor(pc, m); }
  if (lane == 0) {
    out[b] = pr + rb[0];
    out[100 + b] = sigm(pc + cb[0]);
  }
}

// ============================================================================
extern "C" void kernel_launch(void* const* d_in, const int* in_sizes, int n_in,
                              void* d_out, int out_size, void* d_ws, size_t ws_size,
                              hipStream_t stream)
{
  const float* x     = (const float*)d_in[0];
  const float* Wih   = (const float*)d_in[1];
  const float* Whh   = (const float*)d_in[2];
  const float* bih   = (const float*)d_in[3];
  const float* bhh   = (const float*)d_in[4];
  const float* encW  = (const float*)d_in[5];
  const float* encb  = (const float*)d_in[6];
  const float* poolW = (const float*)d_in[7];
  const float* poolb = (const float*)d_in[8];
  const float* innW  = (const float*)d_in[9];
  const float* innas = (const float*)d_in[10];
  const float* innad = (const float*)d_in[11];
  const float* innb  = (const float*)d_in[12];
  const float* catW  = (const float*)d_in[13];
  const float* catas = (const float*)d_in[14];
  const float* catad = (const float*)d_in[15];
  const float* catb  = (const float*)d_in[16];
  const float* fusW  = (const float*)d_in[17];
  const float* fusb  = (const float*)d_in[18];
  const float* regW  = (const float*)d_in[19];
  const float* regb  = (const float*)d_in[20];
  const float* clsW  = (const float*)d_in[21];
  const float* clsb  = (const float*)d_in[22];
  float* out = (float*)d_out;
  char* ws = (char*)d_ws;

  unsigned short* xbf  = (unsigned short*)(ws + OF_XBF);
  unsigned short* hist = (unsigned short*)(ws + OF_HIST);
  int*            flg  = (int*)(ws + OF_FLAGS);
  unsigned short* ewbf = (unsigned short*)(ws + OF_ENCW);
  float* v    = (float*)(ws + OF_V);
  float* hin  = (float*)(ws + OF_HIN);
  float* iemb = (float*)(ws + OF_IEMB);
  float* catv = (float*)(ws + OF_CATV);
  float* cath = (float*)(ws + OF_CATH);
  float* cato = (float*)(ws + OF_CATO);
  float* fbuf = (float*)(ws + OF_FBUF);
  float* fout = (float*)(ws + OF_FOUT);

  hipFuncSetAttribute((const void*)gru_recur, hipFuncAttributeMaxDynamicSharedMemorySize, GRU_LDS);
  hipFuncSetAttribute((const void*)att_pool,  hipFuncAttributeMaxDynamicSharedMemorySize, ATT_LDS);

  // h(0) = 0 (slot 0) and flag reset — stream-ordered, visible at kernel dispatch
  hipMemsetAsync(hist, 0, 204800, stream);
  hipMemsetAsync(flg, 0, 1024, stream);

  f2bf_kernel<<<12800, 256, 0, stream>>>(x, xbf, 13107200 / 4);
  f2bf_kernel<<<256,   256, 0, stream>>>(encW, ewbf, 262144 / 4);

  gru_recur<<<256, 320, GRU_LDS, stream>>>(xbf, Whh, Wih, bih, bhh, hist, flg);
  att_pool<<<1600, 512, ATT_LDS, stream>>>(hist, ewbf, encb, v);

  gemm_bt<<<dim3(16, 7), 256, 0, stream>>>(v, innW, hin, 100, 1024, 1024, nullptr, 0);
  gat_att<20><<<5, 256, 0, stream>>>(hin, innas, innad, innb, iemb);
  pool_att<<<20, 256, 0, stream>>>(v, poolW, poolb, catv);
  gemm_bt<<<dim3(16, 1), 256, 0, stream>>>(catv, catW, cath, 5, 1024, 1024, nullptr, 0);
  gat_att<5><<<1, 256, 0, stream>>>(cath, catas, catad, catb, cato);
  concat_kernel<<<1200, 256, 0, stream>>>(v, cato, iemb, fbuf);
  gemm_bt<<<dim3(16, 7), 256, 0, stream>>>(fbuf, fusW, fout, 100, 1024, 3072, fusb, 1);
  heads<<<25, 256, 0, stream>>>(fout, regW, regb, clsW, clsb, out);

  (void)in_sizes; (void)n_in; (void)out_size; (void)ws_size;
}

// Round 2
// 5428.162 us; speedup vs baseline: 1.1577x; 1.1577x over previous
//
#include <hip/hip_runtime.h>
#include <hip/hip_bf16.h>

// ============================================================================
// CategoricalGraphAtt on MI355X.
// R2: GRU barrier restructured — per-(group,quarter) counters (fan-in 16, waves
// poll independently, wave4 never waits), RELAXED signal (no release/wbl2),
// 2 barriers/step, conflict-free epilogue (ghp col stride 20, thread remap).
// ============================================================================

typedef __bf16 bf16x8 __attribute__((ext_vector_type(8)));
typedef float  floatx4 __attribute__((ext_vector_type(4)));

struct US8 { unsigned short u[8]; };

__device__ __forceinline__ unsigned short f2bf(float f) {
  unsigned u = __builtin_bit_cast(unsigned, f);
  u += 0x7fffu + ((u >> 16) & 1u);           // RNE
  return (unsigned short)(u >> 16);
}
__device__ __forceinline__ float bf2f(unsigned short h) {
  return __builtin_bit_cast(float, ((unsigned)h) << 16);
}
__device__ __forceinline__ float sigm(float x) { return 1.f / (1.f + __expf(-x)); }

// ---------------- workspace layout (bytes) ----------------
static const size_t OF_XBF   = 0;                 // bf16 x [100][512][256]   26,214,400
static const size_t OF_HIST  = 26214400;          // bf16 h_hist [513][100][1024] 105,062,400
static const size_t OF_FLAGS = 131276800;         // int cnt[16] @ 64B stride = 1,024
static const size_t OF_ENCW  = 131277824;         // bf16 enc_att_W [512][512] 524,288
static const size_t OF_V     = 131802112;         // f32 v [100][1024]
static const size_t OF_HIN   = 132211712;         // f32 inner-GAT h
static const size_t OF_IEMB  = 132621312;         // f32 inner_emb
static const size_t OF_CATV  = 133030912;         // f32 cat_vec (pooled) [5][1024]
static const size_t OF_CATH  = 133051392;         // f32 cat-GAT h
static const size_t OF_CATO  = 133071872;         // f32 cat GAT out
static const size_t OF_FBUF  = 133092352;         // f32 fusion input [100][3072]
static const size_t OF_FOUT  = 134321152;         // f32 fusion output [100][1024]

// ---------------- fp32 -> bf16 convert ----------------
__global__ void f2bf_kernel(const float* __restrict__ src, unsigned short* __restrict__ dst, int n4) {
  int i = blockIdx.x * 256 + threadIdx.x;
  if (i < n4) {
    float4 v = ((const float4*)src)[i];
    ushort4 o;
    o.x = f2bf(v.x); o.y = f2bf(v.y); o.z = f2bf(v.z); o.w = f2bf(v.w);
    ((ushort4*)dst)[i] = o;
  }
}

// ---------------- persistent GRU recurrence ----------------
// grid 256 = 4 groups(25 rows) x 64 slices(16 j). block 320 (5 waves).
// waves 0-3: k-steps 8w..8w+8 of h-part (K=1024); wave 4: x-part (K=256).
// LDS: Bw 122880 | bias 256 @122880 | ghp [30][16col][20] f32 @123136 (38400)
//      | hfp [16][25] f32 @161536 (1600). Total 163136 <= 160 KiB.
#define GRU_LDS 163136
__global__ void __launch_bounds__(320) gru_recur(
    const unsigned short* __restrict__ xbf,
    const float* __restrict__ Whh, const float* __restrict__ Wih,
    const float* __restrict__ bih, const float* __restrict__ bhh,
    unsigned short* hist, int* cnt)
{
  extern __shared__ char smem[];
  unsigned short* Bw  = (unsigned short*)smem;       // 61440 bf16 frags
  float* biasl = (float*)(smem + 122880);            // [4][16]: r,z,hn,xn
  float* ghp   = (float*)(smem + 123136);            // [30 blk][16 col][20 (16 rows + pad4)]
  float* hfp   = (float*)(smem + 161536);            // fp32 h state [16 l][25 b]

  const int tid  = threadIdx.x;
  const int lane = tid & 63;
  const int w    = tid >> 6;       // 0..4
  const int wg   = blockIdx.x;
  const int g    = wg >> 6;        // batch group 0..3
  const int s    = wg & 63;        // j slice 0..63
  const int gb   = g * 25;
  const int myq  = s >> 4;         // producer quarter

  // ---- gather B (Whh/Wih rows for this slice) into LDS in frag order ----
  // octets: Brz [2][40][64] | Bnh [32][64] @5120 | Bnx [8][64] @7168
  for (int o = tid; o < 7680; o += 320) {
    int kk, ln; const float* sp; unsigned short* dst;
    if (o < 5120) {
      int q = o >= 2560; int rem = o - q * 2560;
      kk = rem >> 6; ln = rem & 63;
      int l = ln & 15, ksub = ln >> 4, j = s * 16 + l;
      int k = kk * 32 + ksub * 8;
      sp = (k < 1024) ? (Whh + (size_t)(q * 1024 + j) * 1024 + k)
                      : (Wih + (size_t)(q * 1024 + j) * 256 + (k - 1024));
      dst = Bw + ((size_t)((q * 40 + kk) * 64 + ln)) * 8;
    } else if (o < 7168) {
      int o2 = o - 5120; kk = o2 >> 6; ln = o2 & 63;
      int l = ln & 15, ksub = ln >> 4, j = s * 16 + l;
      sp = Whh + (size_t)(2048 + j) * 1024 + kk * 32 + ksub * 8;
      dst = Bw + (size_t)(5120 + kk * 64 + ln) * 8;
    } else {
      int o3 = o - 7168; kk = o3 >> 6; ln = o3 & 63;
      int l = ln & 15, ksub = ln >> 4, j = s * 16 + l;
      sp = Wih + (size_t)(2048 + j) * 256 + kk * 32 + ksub * 8;
      dst = Bw + (size_t)(7168 + kk * 64 + ln) * 8;
    }
    float4 f0 = *(const float4*)sp;
    float4 f1 = *(const float4*)(sp + 4);
    dst[0] = f2bf(f0.x); dst[1] = f2bf(f0.y); dst[2] = f2bf(f0.z); dst[3] = f2bf(f0.w);
    dst[4] = f2bf(f1.x); dst[5] = f2bf(f1.y); dst[6] = f2bf(f1.z); dst[7] = f2bf(f1.w);
  }
  if (tid < 16) {
    int j = s * 16 + tid;
    biasl[tid]      = bih[j]        + bhh[j];
    biasl[16 + tid] = bih[1024 + j] + bhh[1024 + j];
    biasl[32 + tid] = bhh[2048 + j];
    biasl[48 + tid] = bih[2048 + j];
  }
  for (int i = tid; i < 400; i += 320) hfp[i] = 0.f;
  __syncthreads();

  // ---- hoist B fragments (compiler may keep in VGPR/AGPR or re-read LDS) ----
  bf16x8 Breg[24];
  #pragma unroll
  for (int lk = 0; lk < 8; lk++) {
    int kk = w * 8 + lk;
    Breg[lk * 3 + 0] = __builtin_bit_cast(bf16x8, *(const int4*)(Bw + (size_t)((kk)      * 64 + lane) * 8));
    Breg[lk * 3 + 1] = __builtin_bit_cast(bf16x8, *(const int4*)(Bw + (size_t)((40 + kk) * 64 + lane) * 8));
    const unsigned short* np = (w < 4)
        ? (Bw + (size_t)(5120 + kk * 64 + lane) * 8)
        : (Bw + (size_t)(7168 + (kk - 32) * 64 + lane) * 8);
    Breg[lk * 3 + 2] = __builtin_bit_cast(bf16x8, *(const int4*)np);
  }

  const int kfrag = (lane >> 4) * 8;
  size_t rowh[2], rowx[2];
  #pragma unroll
  for (int mt = 0; mt < 2; mt++) {
    int m = mt * 16 + (lane & 15);
    int bb = (m < 25) ? m : 24;           // clamp pad rows
    rowh[mt] = (size_t)(gb + bb) * 1024;
    rowx[mt] = (size_t)(gb + bb) * 512 * 256;
  }

  int* mycnt   = cnt + (g * 4 + myq) * 16;   // producer signal (64B stride)
  int* pollcnt = cnt + (g * 4 + w)   * 16;   // consumer poll (waves 0-3)

  for (int t = 0; t < 512; t++) {
    // ---- wait only for this wave's k-quarter producers (16 WGs) ----
    if (w < 4) {
      const int target = 16 * t;
      while (__hip_atomic_load(pollcnt, __ATOMIC_RELAXED, __HIP_MEMORY_SCOPE_AGENT) < target)
        __builtin_amdgcn_s_sleep(2);
      asm volatile("" ::: "memory");   // no hoisting of h loads above the spin
    }

    const unsigned short* hrow = hist + (size_t)t * 102400;
    floatx4 acc[2][3];
    #pragma unroll
    for (int mt = 0; mt < 2; mt++)
      #pragma unroll
      for (int gg = 0; gg < 3; gg++) acc[mt][gg] = floatx4{0.f, 0.f, 0.f, 0.f};

    #pragma unroll
    for (int lk = 0; lk < 8; lk++) {
      int kk = w * 8 + lk;
      #pragma unroll
      for (int mt = 0; mt < 2; mt++) {
        const unsigned short* ap = (w < 4)
            ? (hrow + rowh[mt] + kk * 32 + kfrag)
            : (xbf + rowx[mt] + (size_t)t * 256 + (kk - 32) * 32 + kfrag);
        bf16x8 a = __builtin_bit_cast(bf16x8, *(const int4*)ap);
        acc[mt][0] = __builtin_amdgcn_mfma_f32_16x16x32_bf16(a, Breg[lk * 3 + 0], acc[mt][0], 0, 0, 0);
        acc[mt][1] = __builtin_amdgcn_mfma_f32_16x16x32_bf16(a, Breg[lk * 3 + 1], acc[mt][1], 0, 0, 0);
        acc[mt][2] = __builtin_amdgcn_mfma_f32_16x16x32_bf16(a, Breg[lk * 3 + 2], acc[mt][2], 0, 0, 0);
      }
    }

    // partials -> LDS: [block][col l][20] with rows contiguous (float4 at q*4)
    {
      int base = (lane & 15) * 20 + (lane >> 4) * 4;
      #pragma unroll
      for (int mt = 0; mt < 2; mt++)
        #pragma unroll
        for (int gg = 0; gg < 3; gg++)
          *(floatx4*)(ghp + (size_t)((w * 2 + mt) * 3 + gg) * 320 + base) = acc[mt][gg];
    }
    __syncthreads();   // (1) partials visible; prev-step epilogue already done

    // ---- epilogue: 256 threads, (lp = col-pair, b = row); <=2-3-way banks ----
    if (tid < 256) {
      int lp = tid >> 5, b = tid & 31;
      if (b < 25) {
        int mt2 = b >> 4, rr = b & 15;
        unsigned packed = 0;
        #pragma unroll
        for (int ii = 0; ii < 2; ii++) {
          int l = lp * 2 + ii;
          int off = l * 20 + rr;
          float ghr = 0.f, ghz = 0.f, ghnh = 0.f, ghnx;
          #pragma unroll
          for (int ww = 0; ww < 4; ww++) {
            const float* gq = ghp + (size_t)((ww * 2 + mt2) * 3) * 320 + off;
            ghr += gq[0]; ghz += gq[320]; ghnh += gq[640];
          }
          { const float* gq = ghp + (size_t)((4 * 2 + mt2) * 3) * 320 + off;
            ghr += gq[0]; ghz += gq[320]; ghnx = gq[640]; }
          float r = sigm(ghr + biasl[l]);
          float z = sigm(ghz + biasl[16 + l]);
          float nv = ghnx + biasl[48 + l] + r * (ghnh + biasl[32 + l]);
          nv = fminf(fmaxf(nv, -15.f), 15.f);
          float e2 = __expf(-2.f * nv);
          float n = (1.f - e2) / (1.f + e2);
          float ho = hfp[l * 25 + b];
          float hn = (1.f - z) * n + z * ho;
          hfp[l * 25 + b] = hn;
          packed |= ((unsigned)f2bf(hn)) << (16 * ii);
        }
        // write-through to MALL (sc0sc1): other XCDs read this next step
        __hip_atomic_store(
            (unsigned*)(hist + (size_t)(t + 1) * 102400 + (size_t)(gb + b) * 1024 + s * 16 + lp * 2),
            packed, __ATOMIC_RELAXED, __HIP_MEMORY_SCOPE_AGENT);
      }
    }
    __syncthreads();   // (2) epilogue LDS reads done; vmcnt(0) drains h' stores

    if (tid == 0 && t < 511)
      __hip_atomic_fetch_add(mycnt, 1, __ATOMIC_RELAXED, __HIP_MEMORY_SCOPE_AGENT);
  }
}

// ---------------- fused time attention ----------------
// grid 1600 (one 64-col block of n'=(b*1024+d)), block 512 (8 waves).
// w[u,n] = sum_t encW[u,t]*hs[t,n] + bt[u]; softmax over u; v[n] = sum p*hs[u,n].
#define ATT_LDS 68096
__global__ void __launch_bounds__(512) att_pool(
    const unsigned short* __restrict__ hist,   // slots 1..512
    const unsigned short* __restrict__ encw,   // bf16 [512][512]
    const float* __restrict__ encb,
    float* __restrict__ vout)
{
  extern __shared__ char smem[];
  unsigned short* Bs = (unsigned short*)smem;          // [16ks][4nt][64lane][8]
  float* red  = (float*)(smem + 65536);                // [8][64]
  float* cmax = (float*)(smem + 65536 + 2048);
  float* csum = (float*)(smem + 65536 + 2048 + 256);

  const int tid = threadIdx.x, w = tid >> 6, lane = tid & 63;
  const int q = lane >> 4, col = lane & 15;
  const int n0 = blockIdx.x * 64;
  const int bg = n0 >> 10, d0 = n0 & 1023;

  // stage hs tile (coalesced [t][d] reads, transposed scatter into frag layout)
  for (int ii = 0; ii < 8; ii++) {
    int c = tid + 512 * ii;
    int t = c >> 3, dd = c & 7;
    int4 li = *(const int4*)(hist + (size_t)(t + 1) * 102400 + (size_t)bg * 1024 + d0 + dd * 8);
    US8 u8 = __builtin_bit_cast(US8, li);
    int kstep = t >> 5, ksub = (t >> 3) & 3, i = t & 7;
    int ntile = dd >> 1, nc0 = (dd & 1) * 8;
    unsigned short* dst = Bs + ((size_t)((kstep * 4 + ntile) * 64 + ksub * 16 + nc0)) * 8 + i;
    #pragma unroll
    for (int jj = 0; jj < 8; jj++) dst[jj * 8] = u8.u[jj];
  }
  __syncthreads();

  floatx4 acc[4][4];
  #pragma unroll
  for (int mi = 0; mi < 4; mi++)
    #pragma unroll
    for (int ni = 0; ni < 4; ni++) acc[mi][ni] = floatx4{0.f, 0.f, 0.f, 0.f};

  #pragma unroll 2
  for (int kk = 0; kk < 16; kk++) {
    int tch = kk * 32 + q * 8;
    bf16x8 af[4];
    #pragma unroll
    for (int mi = 0; mi < 4; mi++) {
      int u = (w * 4 + mi) * 16 + col;
      af[mi] = __builtin_bit_cast(bf16x8, *(const int4*)(encw + (size_t)u * 512 + tch));
    }
    #pragma unroll
    for (int ni = 0; ni < 4; ni++) {
      bf16x8 bf = __builtin_bit_cast(bf16x8, *(const int4*)(Bs + (size_t)((kk * 4 + ni) * 64 + lane) * 8));
      #pragma unroll
      for (int mi = 0; mi < 4; mi++)
        acc[mi][ni] = __builtin_amdgcn_mfma_f32_16x16x32_bf16(af[mi], bf, acc[mi][ni], 0, 0, 0);
    }
  }

  // + row bias
  #pragma unroll
  for (int mi = 0; mi < 4; mi++) {
    int ub = (w * 4 + mi) * 16 + q * 4;
    float b0 = encb[ub], b1 = encb[ub + 1], b2 = encb[ub + 2], b3 = encb[ub + 3];
    #pragma unroll
    for (int ni = 0; ni < 4; ni++) {
      acc[mi][ni][0] += b0; acc[mi][ni][1] += b1; acc[mi][ni][2] += b2; acc[mi][ni][3] += b3;
    }
  }
  // column max
  #pragma unroll
  for (int ni = 0; ni < 4; ni++) {
    float m = -1e30f;
    #pragma unroll
    for (int mi = 0; mi < 4; mi++)
      #pragma unroll
      for (int r = 0; r < 4; r++) m = fmaxf(m, acc[mi][ni][r]);
    m = fmaxf(m, __shfl_xor(m, 16)); m = fmaxf(m, __shfl_xor(m, 32));
    red[w * 64 + ni * 16 + col] = m;
  }
  __syncthreads();
  if (tid < 64) {
    float m = red[tid];
    for (int w2 = 1; w2 < 8; w2++) m = fmaxf(m, red[w2 * 64 + tid]);
    cmax[tid] = m;
  }
  __syncthreads();
  // exp + column sum
  #pragma unroll
  for (int ni = 0; ni < 4; ni++) {
    float cm = cmax[ni * 16 + col];
    float sum = 0.f;
    #pragma unroll
    for (int mi = 0; mi < 4; mi++)
      #pragma unroll
      for (int r = 0; r < 4; r++) {
        float e = __expf(acc[mi][ni][r] - cm);
        acc[mi][ni][r] = e; sum += e;
      }
    sum += __shfl_xor(sum, 16); sum += __shfl_xor(sum, 32);
    red[w * 64 + ni * 16 + col] = sum;
  }
  __syncthreads();
  if (tid < 64) {
    float sm = 0.f;
    for (int w2 = 0; w2 < 8; w2++) sm += red[w2 * 64 + tid];
    csum[tid] = sm;
  }
  __syncthreads();
  // weighted sum of hs
  #pragma unroll
  for (int ni = 0; ni < 4; ni++) {
    float p = 0.f;
    #pragma unroll
    for (int mi = 0; mi < 4; mi++) {
      int u0 = (w * 4 + mi) * 16 + q * 4;
      int ks = u0 >> 5, ksb = (u0 >> 3) & 3, i0 = u0 & 7;
      const unsigned short* hp = Bs + (size_t)((ks * 4 + ni) * 64 + ksb * 16 + col) * 8 + i0;
      p += acc[mi][ni][0] * bf2f(hp[0]) + acc[mi][ni][1] * bf2f(hp[1])
         + acc[mi][ni][2] * bf2f(hp[2]) + acc[mi][ni][3] * bf2f(hp[3]);
    }
    p += __shfl_xor(p, 16); p += __shfl_xor(p, 32);
    red[w * 64 + ni * 16 + col] = p;
  }
  __syncthreads();
  if (tid < 64) {
    float p = 0.f;
    for (int w2 = 0; w2 < 8; w2++) p += red[w2 * 64 + tid];
    vout[n0 + tid] = p / csum[tid];
  }
}

// ---------------- small fp32 GEMM: C(M,N) = A(M,K) @ B(N,K)^T [+bias][+relu] ----------------
__global__ void gemm_bt(const float* __restrict__ A, const float* __restrict__ B,
                        float* __restrict__ C, int M, int N, int K,
                        const float* __restrict__ bias, int relu)
{
  __shared__ float Al[16][33];
  __shared__ float Bl[64][33];
  int tx = threadIdx.x;
  int nb = blockIdx.x, mb = blockIdx.y;
  int n = nb * 64 + (tx & 63);
  int mq = tx >> 6;
  float acc[4] = {0.f, 0.f, 0.f, 0.f};
  for (int k0 = 0; k0 < K; k0 += 32) {
    for (int e = tx; e < 512; e += 256) {
      int r = e >> 5, c = e & 31; int m = mb * 16 + r;
      Al[r][c] = (m < M) ? A[(size_t)m * K + k0 + c] : 0.f;
    }
    for (int e = tx; e < 2048; e += 256) {
      int r = e >> 5, c = e & 31;
      Bl[r][c] = B[(size_t)(nb * 64 + r) * K + k0 + c];
    }
    __syncthreads();
    int nn = tx & 63;
    #pragma unroll 8
    for (int c = 0; c < 32; c++) {
      float bv = Bl[nn][c];
      #pragma unroll
      for (int i = 0; i < 4; i++) acc[i] += Al[mq * 4 + i][c] * bv;
    }
    __syncthreads();
  }
  #pragma unroll
  for (int i = 0; i < 4; i++) {
    int m = mb * 16 + mq * 4 + i;
    if (m < M && n < N) {
      float r = acc[i] + (bias ? bias[n] : 0.f);
      if (relu) r = fmaxf(r, 0.f);
      C[(size_t)m * N + n] = r;
    }
  }
}

// ---------------- GAT attention (complete graph + self loops within each block of NN nodes) ----------------
template <int NN>
__global__ void gat_att(const float* __restrict__ h, const float* __restrict__ asrc,
                        const float* __restrict__ adst, const float* __restrict__ bias,
                        float* __restrict__ out)
{
  __shared__ float asd[2][NN];
  __shared__ float P[NN][NN];
  int c = blockIdx.x, tx = threadIdx.x;
  int wid = tx >> 6, lane = tx & 63;
  for (int idx = wid; idx < 2 * NN; idx += 4) {
    int which = idx >= NN; int j = which ? idx - NN : idx;
    const float* av = which ? adst : asrc;
    float p = 0.f;
    for (int k = lane; k < 1024; k += 64) p += h[(size_t)(c * NN + j) * 1024 + k] * av[k];
    for (int m = 32; m; m >>= 1) p += __shfl_xor(p, m);
    if (lane == 0) asd[which][j] = p;
  }
  __syncthreads();
  if (tx < NN) {
    int i = tx; float mx = -1e30f; float e[NN];
    #pragma unroll
    for (int j = 0; j < NN; j++) {
      float x = asd[0][j] + asd[1][i];
      x = (x < 0.f) ? 0.2f * x : x;
      e[j] = x; mx = fmaxf(mx, x);
    }
    float s = 0.f;
    #pragma unroll
    for (int j = 0; j < NN; j++) { e[j] = __expf(e[j] - mx); s += e[j]; }
    #pragma unroll
    for (int j = 0; j < NN; j++) P[i][j] = e[j] / s;
  }
  __syncthreads();
  for (int ee = tx; ee < NN * 1024; ee += 256) {
    int i = ee >> 10, d = ee & 1023;
    float s = 0.f;
    #pragma unroll
    for (int j = 0; j < NN; j++) s += P[i][j] * h[(size_t)(c * NN + j) * 1024 + d];
    out[(size_t)(c * NN + i) * 1024 + d] = s + bias[d];
  }
}

// ---------------- stock->category pooling attention ----------------
__global__ void pool_att(const float* __restrict__ v, const float* __restrict__ pW,
                         const float* __restrict__ pb, float* __restrict__ catv)
{
  __shared__ float W[400]; __shared__ float bsh[20];
  int tx = threadIdx.x;
  for (int i = tx; i < 400; i += 256) W[i] = pW[i];
  if (tx < 20) bsh[tx] = pb[tx];
  __syncthreads();
  int gid = blockIdx.x * 256 + tx;
  int c = gid >> 10, d = gid & 1023;
  float vals[20];
  #pragma unroll
  for (int t = 0; t < 20; t++) vals[t] = v[(size_t)(c * 20 + t) * 1024 + d];
  float wv[20]; float mx = -1e30f;
  #pragma unroll
  for (int u = 0; u < 20; u++) {
    float s = bsh[u];
    #pragma unroll
    for (int t = 0; t < 20; t++) s += vals[t] * W[u * 20 + t];
    wv[u] = s; mx = fmaxf(mx, s);
  }
  float sum = 0.f, out = 0.f;
  #pragma unroll
  for (int u = 0; u < 20; u++) { float e = __expf(wv[u] - mx); sum += e; out += e * vals[u]; }
  catv[gid] = out / sum;
}

// ---------------- fusion concat ----------------
__global__ void concat_kernel(const float* __restrict__ v, const float* __restrict__ cato,
                              const float* __restrict__ iemb, float* __restrict__ F)
{
  int gid = blockIdx.x * 256 + threadIdx.x;
  if (gid < 307200) {
    int i = gid / 3072;
    int k = gid - i * 3072;
    float r;
    if (k < 1024)       r = v[(size_t)i * 1024 + k];
    else if (k < 2048)  r = cato[(size_t)(i / 20) * 1024 + (k - 1024)];
    else                r = iemb[(size_t)i * 1024 + (k - 2048)];
    F[gid] = r;
  }
}

// ---------------- output heads ----------------
__global__ void heads(const float* __restrict__ f, const float* __restrict__ rw,
                      const float* __restrict__ rb, const float* __restrict__ cw,
                      const float* __restrict__ cb, float* __restrict__ out)
{
  int b = blockIdx.x * 4 + (threadIdx.x >> 6);
  int lane = threadIdx.x & 63;
  float pr = 0.f, pc = 0.f;
  for (int k = lane; k < 1024; k += 64) {
    float x = f[(size_t)b * 1024 + k];
    pr += x * rw[k]; pc += x * cw[k];
  }
  for (int m = 32; m; m >>= 1) { pr += __shfl_xor(pr, m); pc += __shfl_xor(pc, m); }
  if (lane == 0) {
    out[b] = pr + rb[0];
    out[100 + b] = sigm(pc + cb[0]);
  }
}

// ============================================================================
extern "C" void kernel_launch(void* const* d_in, const int* in_sizes, int n_in,
                              void* d_out, int out_size, void* d_ws, size_t ws_size,
                              hipStream_t stream)
{
  const float* x     = (const float*)d_in[0];
  const float* Wih   = (const float*)d_in[1];
  const float* Whh   = (const float*)d_in[2];
  const float* bih   = (const float*)d_in[3];
  const float* bhh   = (const float*)d_in[4];
  const float* encW  = (const float*)d_in[5];
  const float* encb  = (const float*)d_in[6];
  const float* poolW = (const float*)d_in[7];
  const float* poolb = (const float*)d_in[8];
  const float* innW  = (const float*)d_in[9];
  const float* innas = (const float*)d_in[10];
  const float* innad = (const float*)d_in[11];
  const float* innb  = (const float*)d_in[12];
  const float* catW  = (const float*)d_in[13];
  const float* catas = (const float*)d_in[14];
  const float* catad = (const float*)d_in[15];
  const float* catb  = (const float*)d_in[16];
  const float* fusW  = (const float*)d_in[17];
  const float* fusb  = (const float*)d_in[18];
  const float* regW  = (const float*)d_in[19];
  const float* regb  = (const float*)d_in[20];
  const float* clsW  = (const float*)d_in[21];
  const float* clsb  = (const float*)d_in[22];
  float* out = (float*)d_out;
  char* ws = (char*)d_ws;

  unsigned short* xbf  = (unsigned short*)(ws + OF_XBF);
  unsigned short* hist = (unsigned short*)(ws + OF_HIST);
  int*            flg  = (int*)(ws + OF_FLAGS);
  unsigned short* ewbf = (unsigned short*)(ws + OF_ENCW);
  float* v    = (float*)(ws + OF_V);
  float* hin  = (float*)(ws + OF_HIN);
  float* iemb = (float*)(ws + OF_IEMB);
  float* catv = (float*)(ws + OF_CATV);
  float* cath = (float*)(ws + OF_CATH);
  float* cato = (float*)(ws + OF_CATO);
  float* fbuf = (float*)(ws + OF_FBUF);
  float* fout = (float*)(ws + OF_FOUT);

  hipFuncSetAttribute((const void*)gru_recur, hipFuncAttributeMaxDynamicSharedMemorySize, GRU_LDS);
  hipFuncSetAttribute((const void*)att_pool,  hipFuncAttributeMaxDynamicSharedMemorySize, ATT_LDS);

  // h(0) = 0 (slot 0) and counter reset — stream-ordered, visible at kernel dispatch
  hipMemsetAsync(hist, 0, 204800, stream);
  hipMemsetAsync(flg, 0, 1024, stream);

  f2bf_kernel<<<12800, 256, 0, stream>>>(x, xbf, 13107200 / 4);
  f2bf_kernel<<<256,   256, 0, stream>>>(encW, ewbf, 262144 / 4);

  gru_recur<<<256, 320, GRU_LDS, stream>>>(xbf, Whh, Wih, bih, bhh, hist, flg);
  att_pool<<<1600, 512, ATT_LDS, stream>>>(hist, ewbf, encb, v);

  gemm_bt<<<dim3(16, 7), 256, 0, stream>>>(v, innW, hin, 100, 1024, 1024, nullptr, 0);
  gat_att<20><<<5, 256, 0, stream>>>(hin, innas, innad, innb, iemb);
  pool_att<<<20, 256, 0, stream>>>(v, poolW, poolb, catv);
  gemm_bt<<<dim3(16, 1), 256, 0, stream>>>(catv, catW, cath, 5, 1024, 1024, nullptr, 0);
  gat_att<5><<<1, 256, 0, stream>>>(cath, catas, catad, catb, cato);
  concat_kernel<<<1200, 256, 0, stream>>>(v, cato, iemb, fbuf);
  gemm_bt<<<dim3(16, 7), 256, 0, stream>>>(fbuf, fusW, fout, 100, 1024, 3072, fusb, 1);
  heads<<<25, 256, 0, stream>>>(fout, regW, regb, clsW, clsb, out);

  (void)in_sizes; (void)n_in; (void)out_size; (void)ws_size;
}

// Round 3
// 5139.374 us; speedup vs baseline: 1.2228x; 1.0562x over previous
//
#include <hip/hip_runtime.h>
#include <hip/hip_bf16.h>

// ============================================================================
// CategoricalGraphAtt on MI355X.
// R3: GRU sync minimized — raw s_barrier (lgkm-only at bar1: no vmcnt drain of
// the old flag ack), plain per-WG flag stores (no RMW serialization), consumer
// polls a whole 16-flag line with one coalesced 64B agent load + ballot.
// ============================================================================

typedef __bf16 bf16x8 __attribute__((ext_vector_type(8)));
typedef float  floatx4 __attribute__((ext_vector_type(4)));

struct US8 { unsigned short u[8]; };

__device__ __forceinline__ unsigned short f2bf(float f) {
  unsigned u = __builtin_bit_cast(unsigned, f);
  u += 0x7fffu + ((u >> 16) & 1u);           // RNE
  return (unsigned short)(u >> 16);
}
__device__ __forceinline__ float bf2f(unsigned short h) {
  return __builtin_bit_cast(float, ((unsigned)h) << 16);
}
__device__ __forceinline__ float sigm(float x) { return 1.f / (1.f + __expf(-x)); }

// raw barriers: LDS-only ordering (no vmcnt drain) / full drain
__device__ __forceinline__ void bar_lds() {
  asm volatile("s_waitcnt lgkmcnt(0)" ::: "memory");
  __builtin_amdgcn_s_barrier();
  asm volatile("" ::: "memory");
}
__device__ __forceinline__ void bar_full() {
  asm volatile("s_waitcnt vmcnt(0) lgkmcnt(0)" ::: "memory");
  __builtin_amdgcn_s_barrier();
  asm volatile("" ::: "memory");
}

// ---------------- workspace layout (bytes) ----------------
static const size_t OF_XBF   = 0;                 // bf16 x [100][512][256]   26,214,400
static const size_t OF_HIST  = 26214400;          // bf16 h_hist [513][100][1024] 105,062,400
static const size_t OF_FLAGS = 131276800;         // int flags[16 lines][16] = 1,024
static const size_t OF_ENCW  = 131277824;         // bf16 enc_att_W [512][512] 524,288
static const size_t OF_V     = 131802112;         // f32 v [100][1024]
static const size_t OF_HIN   = 132211712;         // f32 inner-GAT h
static const size_t OF_IEMB  = 132621312;         // f32 inner_emb
static const size_t OF_CATV  = 133030912;         // f32 cat_vec (pooled) [5][1024]
static const size_t OF_CATH  = 133051392;         // f32 cat-GAT h
static const size_t OF_CATO  = 133071872;         // f32 cat GAT out
static const size_t OF_FBUF  = 133092352;         // f32 fusion input [100][3072]
static const size_t OF_FOUT  = 134321152;         // f32 fusion output [100][1024]

// ---------------- fp32 -> bf16 convert ----------------
__global__ void f2bf_kernel(const float* __restrict__ src, unsigned short* __restrict__ dst, int n4) {
  int i = blockIdx.x * 256 + threadIdx.x;
  if (i < n4) {
    float4 v = ((const float4*)src)[i];
    ushort4 o;
    o.x = f2bf(v.x); o.y = f2bf(v.y); o.z = f2bf(v.z); o.w = f2bf(v.w);
    ((ushort4*)dst)[i] = o;
  }
}

// ---------------- persistent GRU recurrence ----------------
// grid 256 = 4 groups(25 rows) x 64 slices(16 j). block 320 (5 waves).
// waves 0-3: k-steps 8w..8w+8 of h-part (K=1024); wave 4: x-part (K=256).
// LDS: Bw 122880 | bias 256 @122880 | ghp [30][16col][20] f32 @123136 (38400)
//      | hfp [16][25] f32 @161536 (1600). Total 163136 <= 160 KiB.
#define GRU_LDS 163136
__global__ void __launch_bounds__(320) gru_recur(
    const unsigned short* __restrict__ xbf,
    const float* __restrict__ Whh, const float* __restrict__ Wih,
    const float* __restrict__ bih, const float* __restrict__ bhh,
    unsigned short* hist, int* flags)
{
  extern __shared__ char smem[];
  unsigned short* Bw  = (unsigned short*)smem;       // 61440 bf16 frags
  float* biasl = (float*)(smem + 122880);            // [4][16]: r,z,hn,xn
  float* ghp   = (float*)(smem + 123136);            // [30 blk][16 col][20 (16 rows + pad4)]
  float* hfp   = (float*)(smem + 161536);            // fp32 h state [16 l][25 b]

  const int tid  = threadIdx.x;
  const int lane = tid & 63;
  const int w    = tid >> 6;       // 0..4
  const int wg   = blockIdx.x;
  const int g    = wg >> 6;        // batch group 0..3
  const int s    = wg & 63;        // j slice 0..63
  const int gb   = g * 25;
  const int myq  = s >> 4;         // producer quarter

  // ---- gather B (Whh/Wih rows for this slice) into LDS in frag order ----
  // octets: Brz [2][40][64] | Bnh [32][64] @5120 | Bnx [8][64] @7168
  for (int o = tid; o < 7680; o += 320) {
    int kk, ln; const float* sp; unsigned short* dst;
    if (o < 5120) {
      int q = o >= 2560; int rem = o - q * 2560;
      kk = rem >> 6; ln = rem & 63;
      int l = ln & 15, ksub = ln >> 4, j = s * 16 + l;
      int k = kk * 32 + ksub * 8;
      sp = (k < 1024) ? (Whh + (size_t)(q * 1024 + j) * 1024 + k)
                      : (Wih + (size_t)(q * 1024 + j) * 256 + (k - 1024));
      dst = Bw + ((size_t)((q * 40 + kk) * 64 + ln)) * 8;
    } else if (o < 7168) {
      int o2 = o - 5120; kk = o2 >> 6; ln = o2 & 63;
      int l = ln & 15, ksub = ln >> 4, j = s * 16 + l;
      sp = Whh + (size_t)(2048 + j) * 1024 + kk * 32 + ksub * 8;
      dst = Bw + (size_t)(5120 + kk * 64 + ln) * 8;
    } else {
      int o3 = o - 7168; kk = o3 >> 6; ln = o3 & 63;
      int l = ln & 15, ksub = ln >> 4, j = s * 16 + l;
      sp = Wih + (size_t)(2048 + j) * 256 + kk * 32 + ksub * 8;
      dst = Bw + (size_t)(7168 + kk * 64 + ln) * 8;
    }
    float4 f0 = *(const float4*)sp;
    float4 f1 = *(const float4*)(sp + 4);
    dst[0] = f2bf(f0.x); dst[1] = f2bf(f0.y); dst[2] = f2bf(f0.z); dst[3] = f2bf(f0.w);
    dst[4] = f2bf(f1.x); dst[5] = f2bf(f1.y); dst[6] = f2bf(f1.z); dst[7] = f2bf(f1.w);
  }
  if (tid < 16) {
    int j = s * 16 + tid;
    biasl[tid]      = bih[j]        + bhh[j];
    biasl[16 + tid] = bih[1024 + j] + bhh[1024 + j];
    biasl[32 + tid] = bhh[2048 + j];
    biasl[48 + tid] = bih[2048 + j];
  }
  for (int i = tid; i < 400; i += 320) hfp[i] = 0.f;
  __syncthreads();

  // ---- hoist B fragments (persist across all 512 steps) ----
  bf16x8 Breg[24];
  #pragma unroll
  for (int lk = 0; lk < 8; lk++) {
    int kk = w * 8 + lk;
    Breg[lk * 3 + 0] = __builtin_bit_cast(bf16x8, *(const int4*)(Bw + (size_t)((kk)      * 64 + lane) * 8));
    Breg[lk * 3 + 1] = __builtin_bit_cast(bf16x8, *(const int4*)(Bw + (size_t)((40 + kk) * 64 + lane) * 8));
    const unsigned short* np = (w < 4)
        ? (Bw + (size_t)(5120 + kk * 64 + lane) * 8)
        : (Bw + (size_t)(7168 + (kk - 32) * 64 + lane) * 8);
    Breg[lk * 3 + 2] = __builtin_bit_cast(bf16x8, *(const int4*)np);
  }

  const int kfrag = (lane >> 4) * 8;
  size_t rowh[2], rowx[2];
  #pragma unroll
  for (int mt = 0; mt < 2; mt++) {
    int m = mt * 16 + (lane & 15);
    int bb = (m < 25) ? m : 24;           // clamp pad rows
    rowh[mt] = (size_t)(gb + bb) * 1024;
    rowx[mt] = (size_t)(gb + bb) * 512 * 256;
  }

  // flag layout: line (g*4+q) of 16 ints (64B); slot s&15. Producer stores t+1
  // after h(t+1) is drained; consumer wave w polls line (g*4+w) for >= t.
  int* myflag   = flags + (g * 4 + myq) * 16 + (s & 15);
  const int* pollline = flags + (g * 4 + w) * 16;

  for (int t = 0; t < 512; t++) {
    // ---- wait for this wave's k-quarter producers (one 64B load + ballot) ----
    if (w < 4) {
      for (;;) {
        int f = __hip_atomic_load(pollline + (lane & 15), __ATOMIC_RELAXED, __HIP_MEMORY_SCOPE_AGENT);
        if (__all(f >= t)) break;
        __builtin_amdgcn_s_sleep(1);
      }
      asm volatile("" ::: "memory");   // no hoisting of h loads above the spin
    }

    const unsigned short* hrow = hist + (size_t)t * 102400;
    floatx4 acc[2][3];
    #pragma unroll
    for (int mt = 0; mt < 2; mt++)
      #pragma unroll
      for (int gg = 0; gg < 3; gg++) acc[mt][gg] = floatx4{0.f, 0.f, 0.f, 0.f};

    #pragma unroll
    for (int lk = 0; lk < 8; lk++) {
      int kk = w * 8 + lk;
      #pragma unroll
      for (int mt = 0; mt < 2; mt++) {
        const unsigned short* ap = (w < 4)
            ? (hrow + rowh[mt] + kk * 32 + kfrag)
            : (xbf + rowx[mt] + (size_t)t * 256 + (kk - 32) * 32 + kfrag);
        bf16x8 a = __builtin_bit_cast(bf16x8, *(const int4*)ap);
        acc[mt][0] = __builtin_amdgcn_mfma_f32_16x16x32_bf16(a, Breg[lk * 3 + 0], acc[mt][0], 0, 0, 0);
        acc[mt][1] = __builtin_amdgcn_mfma_f32_16x16x32_bf16(a, Breg[lk * 3 + 1], acc[mt][1], 0, 0, 0);
        acc[mt][2] = __builtin_amdgcn_mfma_f32_16x16x32_bf16(a, Breg[lk * 3 + 2], acc[mt][2], 0, 0, 0);
      }
    }

    // partials -> LDS: [block][col l][20] with rows contiguous (float4 at q*4)
    {
      int base = (lane & 15) * 20 + (lane >> 4) * 4;
      #pragma unroll
      for (int mt = 0; mt < 2; mt++)
        #pragma unroll
        for (int gg = 0; gg < 3; gg++)
          *(floatx4*)(ghp + (size_t)((w * 2 + mt) * 3 + gg) * 320 + base) = acc[mt][gg];
    }
    bar_lds();   // (1) partials visible — LDS-only, no vmcnt drain

    // ---- epilogue: 256 threads, (lp = col-pair, b = row) ----
    if (tid < 256) {
      int lp = tid >> 5, b = tid & 31;
      if (b < 25) {
        int mt2 = b >> 4, rr = b & 15;
        unsigned packed = 0;
        #pragma unroll
        for (int ii = 0; ii < 2; ii++) {
          int l = lp * 2 + ii;
          int off = l * 20 + rr;
          float ghr = 0.f, ghz = 0.f, ghnh = 0.f, ghnx;
          #pragma unroll
          for (int ww = 0; ww < 4; ww++) {
            const float* gq = ghp + (size_t)((ww * 2 + mt2) * 3) * 320 + off;
            ghr += gq[0]; ghz += gq[320]; ghnh += gq[640];
          }
          { const float* gq = ghp + (size_t)((4 * 2 + mt2) * 3) * 320 + off;
            ghr += gq[0]; ghz += gq[320]; ghnx = gq[640]; }
          float r = sigm(ghr + biasl[l]);
          float z = sigm(ghz + biasl[16 + l]);
          float nv = ghnx + biasl[48 + l] + r * (ghnh + biasl[32 + l]);
          nv = fminf(fmaxf(nv, -15.f), 15.f);
          float e2 = __expf(-2.f * nv);
          float n = (1.f - e2) / (1.f + e2);
          float ho = hfp[l * 25 + b];
          float hn = (1.f - z) * n + z * ho;
          hfp[l * 25 + b] = hn;
          packed |= ((unsigned)f2bf(hn)) << (16 * ii);
        }
        // write-through to MALL: other XCDs read this next step
        __hip_atomic_store(
            (unsigned*)(hist + (size_t)(t + 1) * 102400 + (size_t)(gb + b) * 1024 + s * 16 + lp * 2),
            packed, __ATOMIC_RELAXED, __HIP_MEMORY_SCOPE_AGENT);
      }
    }
    bar_full();  // (2) epilogue LDS reads done + h' stores drained (vmcnt(0))

    if (tid == 0 && t < 511)
      __hip_atomic_store(myflag, t + 1, __ATOMIC_RELAXED, __HIP_MEMORY_SCOPE_AGENT);
  }
}

// ---------------- fused time attention ----------------
// grid 1600 (one 64-col block of n'=(b*1024+d)), block 512 (8 waves).
// w[u,n] = sum_t encW[u,t]*hs[t,n] + bt[u]; softmax over u; v[n] = sum p*hs[u,n].
#define ATT_LDS 68096
__global__ void __launch_bounds__(512) att_pool(
    const unsigned short* __restrict__ hist,   // slots 1..512
    const unsigned short* __restrict__ encw,   // bf16 [512][512]
    const float* __restrict__ encb,
    float* __restrict__ vout)
{
  extern __shared__ char smem[];
  unsigned short* Bs = (unsigned short*)smem;          // [16ks][4nt][64lane][8]
  float* red  = (float*)(smem + 65536);                // [8][64]
  float* cmax = (float*)(smem + 65536 + 2048);
  float* csum = (float*)(smem + 65536 + 2048 + 256);

  const int tid = threadIdx.x, w = tid >> 6, lane = tid & 63;
  const int q = lane >> 4, col = lane & 15;
  const int n0 = blockIdx.x * 64;
  const int bg = n0 >> 10, d0 = n0 & 1023;

  // stage hs tile (coalesced [t][d] reads, transposed scatter into frag layout)
  for (int ii = 0; ii < 8; ii++) {
    int c = tid + 512 * ii;
    int t = c >> 3, dd = c & 7;
    int4 li = *(const int4*)(hist + (size_t)(t + 1) * 102400 + (size_t)bg * 1024 + d0 + dd * 8);
    US8 u8 = __builtin_bit_cast(US8, li);
    int kstep = t >> 5, ksub = (t >> 3) & 3, i = t & 7;
    int ntile = dd >> 1, nc0 = (dd & 1) * 8;
    unsigned short* dst = Bs + ((size_t)((kstep * 4 + ntile) * 64 + ksub * 16 + nc0)) * 8 + i;
    #pragma unroll
    for (int jj = 0; jj < 8; jj++) dst[jj * 8] = u8.u[jj];
  }
  __syncthreads();

  floatx4 acc[4][4];
  #pragma unroll
  for (int mi = 0; mi < 4; mi++)
    #pragma unroll
    for (int ni = 0; ni < 4; ni++) acc[mi][ni] = floatx4{0.f, 0.f, 0.f, 0.f};

  #pragma unroll 2
  for (int kk = 0; kk < 16; kk++) {
    int tch = kk * 32 + q * 8;
    bf16x8 af[4];
    #pragma unroll
    for (int mi = 0; mi < 4; mi++) {
      int u = (w * 4 + mi) * 16 + col;
      af[mi] = __builtin_bit_cast(bf16x8, *(const int4*)(encw + (size_t)u * 512 + tch));
    }
    #pragma unroll
    for (int ni = 0; ni < 4; ni++) {
      bf16x8 bf = __builtin_bit_cast(bf16x8, *(const int4*)(Bs + (size_t)((kk * 4 + ni) * 64 + lane) * 8));
      #pragma unroll
      for (int mi = 0; mi < 4; mi++)
        acc[mi][ni] = __builtin_amdgcn_mfma_f32_16x16x32_bf16(af[mi], bf, acc[mi][ni], 0, 0, 0);
    }
  }

  // + row bias
  #pragma unroll
  for (int mi = 0; mi < 4; mi++) {
    int ub = (w * 4 + mi) * 16 + q * 4;
    float b0 = encb[ub], b1 = encb[ub + 1], b2 = encb[ub + 2], b3 = encb[ub + 3];
    #pragma unroll
    for (int ni = 0; ni < 4; ni++) {
      acc[mi][ni][0] += b0; acc[mi][ni][1] += b1; acc[mi][ni][2] += b2; acc[mi][ni][3] += b3;
    }
  }
  // column max
  #pragma unroll
  for (int ni = 0; ni < 4; ni++) {
    float m = -1e30f;
    #pragma unroll
    for (int mi = 0; mi < 4; mi++)
      #pragma unroll
      for (int r = 0; r < 4; r++) m = fmaxf(m, acc[mi][ni][r]);
    m = fmaxf(m, __shfl_xor(m, 16)); m = fmaxf(m, __shfl_xor(m, 32));
    red[w * 64 + ni * 16 + col] = m;
  }
  __syncthreads();
  if (tid < 64) {
    float m = red[tid];
    for (int w2 = 1; w2 < 8; w2++) m = fmaxf(m, red[w2 * 64 + tid]);
    cmax[tid] = m;
  }
  __syncthreads();
  // exp + column sum
  #pragma unroll
  for (int ni = 0; ni < 4; ni++) {
    float cm = cmax[ni * 16 + col];
    float sum = 0.f;
    #pragma unroll
    for (int mi = 0; mi < 4; mi++)
      #pragma unroll
      for (int r = 0; r < 4; r++) {
        float e = __expf(acc[mi][ni][r] - cm);
        acc[mi][ni][r] = e; sum += e;
      }
    sum += __shfl_xor(sum, 16); sum += __shfl_xor(sum, 32);
    red[w * 64 + ni * 16 + col] = sum;
  }
  __syncthreads();
  if (tid < 64) {
    float sm = 0.f;
    for (int w2 = 0; w2 < 8; w2++) sm += red[w2 * 64 + tid];
    csum[tid] = sm;
  }
  __syncthreads();
  // weighted sum of hs
  #pragma unroll
  for (int ni = 0; ni < 4; ni++) {
    float p = 0.f;
    #pragma unroll
    for (int mi = 0; mi < 4; mi++) {
      int u0 = (w * 4 + mi) * 16 + q * 4;
      int ks = u0 >> 5, ksb = (u0 >> 3) & 3, i0 = u0 & 7;
      const unsigned short* hp = Bs + (size_t)((ks * 4 + ni) * 64 + ksb * 16 + col) * 8 + i0;
      p += acc[mi][ni][0] * bf2f(hp[0]) + acc[mi][ni][1] * bf2f(hp[1])
         + acc[mi][ni][2] * bf2f(hp[2]) + acc[mi][ni][3] * bf2f(hp[3]);
    }
    p += __shfl_xor(p, 16); p += __shfl_xor(p, 32);
    red[w * 64 + ni * 16 + col] = p;
  }
  __syncthreads();
  if (tid < 64) {
    float p = 0.f;
    for (int w2 = 0; w2 < 8; w2++) p += red[w2 * 64 + tid];
    vout[n0 + tid] = p / csum[tid];
  }
}

// ---------------- small fp32 GEMM: C(M,N) = A(M,K) @ B(N,K)^T [+bias][+relu] ----------------
__global__ void gemm_bt(const float* __restrict__ A, const float* __restrict__ B,
                        float* __restrict__ C, int M, int N, int K,
                        const float* __restrict__ bias, int relu)
{
  __shared__ float Al[16][33];
  __shared__ float Bl[64][33];
  int tx = threadIdx.x;
  int nb = blockIdx.x, mb = blockIdx.y;
  int n = nb * 64 + (tx & 63);
  int mq = tx >> 6;
  float acc[4] = {0.f, 0.f, 0.f, 0.f};
  for (int k0 = 0; k0 < K; k0 += 32) {
    for (int e = tx; e < 512; e += 256) {
      int r = e >> 5, c = e & 31; int m = mb * 16 + r;
      Al[r][c] = (m < M) ? A[(size_t)m * K + k0 + c] : 0.f;
    }
    for (int e = tx; e < 2048; e += 256) {
      int r = e >> 5, c = e & 31;
      Bl[r][c] = B[(size_t)(nb * 64 + r) * K + k0 + c];
    }
    __syncthreads();
    int nn = tx & 63;
    #pragma unroll 8
    for (int c = 0; c < 32; c++) {
      float bv = Bl[nn][c];
      #pragma unroll
      for (int i = 0; i < 4; i++) acc[i] += Al[mq * 4 + i][c] * bv;
    }
    __syncthreads();
  }
  #pragma unroll
  for (int i = 0; i < 4; i++) {
    int m = mb * 16 + mq * 4 + i;
    if (m < M && n < N) {
      float r = acc[i] + (bias ? bias[n] : 0.f);
      if (relu) r = fmaxf(r, 0.f);
      C[(size_t)m * N + n] = r;
    }
  }
}

// ---------------- GAT attention (complete graph + self loops within each block of NN nodes) ----------------
template <int NN>
__global__ void gat_att(const float* __restrict__ h, const float* __restrict__ asrc,
                        const float* __restrict__ adst, const float* __restrict__ bias,
                        float* __restrict__ out)
{
  __shared__ float asd[2][NN];
  __shared__ float P[NN][NN];
  int c = blockIdx.x, tx = threadIdx.x;
  int wid = tx >> 6, lane = tx & 63;
  for (int idx = wid; idx < 2 * NN; idx += 4) {
    int which = idx >= NN; int j = which ? idx - NN : idx;
    const float* av = which ? adst : asrc;
    float p = 0.f;
    for (int k = lane; k < 1024; k += 64) p += h[(size_t)(c * NN + j) * 1024 + k] * av[k];
    for (int m = 32; m; m >>= 1) p += __shfl_xor(p, m);
    if (lane == 0) asd[which][j] = p;
  }
  __syncthreads();
  if (tx < NN) {
    int i = tx; float mx = -1e30f; float e[NN];
    #pragma unroll
    for (int j = 0; j < NN; j++) {
      float x = asd[0][j] + asd[1][i];
      x = (x < 0.f) ? 0.2f * x : x;
      e[j] = x; mx = fmaxf(mx, x);
    }
    float s = 0.f;
    #pragma unroll
    for (int j = 0; j < NN; j++) { e[j] = __expf(e[j] - mx); s += e[j]; }
    #pragma unroll
    for (int j = 0; j < NN; j++) P[i][j] = e[j] / s;
  }
  __syncthreads();
  for (int ee = tx; ee < NN * 1024; ee += 256) {
    int i = ee >> 10, d = ee & 1023;
    float s = 0.f;
    #pragma unroll
    for (int j = 0; j < NN; j++) s += P[i][j] * h[(size_t)(c * NN + j) * 1024 + d];
    out[(size_t)(c * NN + i) * 1024 + d] = s + bias[d];
  }
}

// ---------------- stock->category pooling attention ----------------
__global__ void pool_att(const float* __restrict__ v, const float* __restrict__ pW,
                         const float* __restrict__ pb, float* __restrict__ catv)
{
  __shared__ float W[400]; __shared__ float bsh[20];
  int tx = threadIdx.x;
  for (int i = tx; i < 400; i += 256) W[i] = pW[i];
  if (tx < 20) bsh[tx] = pb[tx];
  __syncthreads();
  int gid = blockIdx.x * 256 + tx;
  int c = gid >> 10, d = gid & 1023;
  float vals[20];
  #pragma unroll
  for (int t = 0; t < 20; t++) vals[t] = v[(size_t)(c * 20 + t) * 1024 + d];
  float wv[20]; float mx = -1e30f;
  #pragma unroll
  for (int u = 0; u < 20; u++) {
    float s = bsh[u];
    #pragma unroll
    for (int t = 0; t < 20; t++) s += vals[t] * W[u * 20 + t];
    wv[u] = s; mx = fmaxf(mx, s);
  }
  float sum = 0.f, out = 0.f;
  #pragma unroll
  for (int u = 0; u < 20; u++) { float e = __expf(wv[u] - mx); sum += e; out += e * vals[u]; }
  catv[gid] = out / sum;
}

// ---------------- fusion concat ----------------
__global__ void concat_kernel(const float* __restrict__ v, const float* __restrict__ cato,
                              const float* __restrict__ iemb, float* __restrict__ F)
{
  int gid = blockIdx.x * 256 + threadIdx.x;
  if (gid < 307200) {
    int i = gid / 3072;
    int k = gid - i * 3072;
    float r;
    if (k < 1024)       r = v[(size_t)i * 1024 + k];
    else if (k < 2048)  r = cato[(size_t)(i / 20) * 1024 + (k - 1024)];
    else                r = iemb[(size_t)i * 1024 + (k - 2048)];
    F[gid] = r;
  }
}

// ---------------- output heads ----------------
__global__ void heads(const float* __restrict__ f, const float* __restrict__ rw,
                      const float* __restrict__ rb, const float* __restrict__ cw,
                      const float* __restrict__ cb, float* __restrict__ out)
{
  int b = blockIdx.x * 4 + (threadIdx.x >> 6);
  int lane = threadIdx.x & 63;
  float pr = 0.f, pc = 0.f;
  for (int k = lane; k < 1024; k += 64) {
    float x = f[(size_t)b * 1024 + k];
    pr += x * rw[k]; pc += x * cw[k];
  }
  for (int m = 32; m; m >>= 1) { pr += __shfl_xor(pr, m); pc += __shfl_xor(pc, m); }
  if (lane == 0) {
    out[b] = pr + rb[0];
    out[100 + b] = sigm(pc + cb[0]);
  }
}

// ============================================================================
extern "C" void kernel_launch(void* const* d_in, const int* in_sizes, int n_in,
                              void* d_out, int out_size, void* d_ws, size_t ws_size,
                              hipStream_t stream)
{
  const float* x     = (const float*)d_in[0];
  const float* Wih   = (const float*)d_in[1];
  const float* Whh   = (const float*)d_in[2];
  const float* bih   = (const float*)d_in[3];
  const float* bhh   = (const float*)d_in[4];
  const float* encW  = (const float*)d_in[5];
  const float* encb  = (const float*)d_in[6];
  const float* poolW = (const float*)d_in[7];
  const float* poolb = (const float*)d_in[8];
  const float* innW  = (const float*)d_in[9];
  const float* innas = (const float*)d_in[10];
  const float* innad = (const float*)d_in[11];
  const float* innb  = (const float*)d_in[12];
  const float* catW  = (const float*)d_in[13];
  const float* catas = (const float*)d_in[14];
  const float* catad = (const float*)d_in[15];
  const float* catb  = (const float*)d_in[16];
  const float* fusW  = (const float*)d_in[17];
  const float* fusb  = (const float*)d_in[18];
  const float* regW  = (const float*)d_in[19];
  const float* regb  = (const float*)d_in[20];
  const float* clsW  = (const float*)d_in[21];
  const float* clsb  = (const float*)d_in[22];
  float* out = (float*)d_out;
  char* ws = (char*)d_ws;

  unsigned short* xbf  = (unsigned short*)(ws + OF_XBF);
  unsigned short* hist = (unsigned short*)(ws + OF_HIST);
  int*            flg  = (int*)(ws + OF_FLAGS);
  unsigned short* ewbf = (unsigned short*)(ws + OF_ENCW);
  float* v    = (float*)(ws + OF_V);
  float* hin  = (float*)(ws + OF_HIN);
  float* iemb = (float*)(ws + OF_IEMB);
  float* catv = (float*)(ws + OF_CATV);
  float* cath = (float*)(ws + OF_CATH);
  float* cato = (float*)(ws + OF_CATO);
  float* fbuf = (float*)(ws + OF_FBUF);
  float* fout = (float*)(ws + OF_FOUT);

  hipFuncSetAttribute((const void*)gru_recur, hipFuncAttributeMaxDynamicSharedMemorySize, GRU_LDS);
  hipFuncSetAttribute((const void*)att_pool,  hipFuncAttributeMaxDynamicSharedMemorySize, ATT_LDS);

  // h(0) = 0 (slot 0) and flag reset — stream-ordered, visible at kernel dispatch
  hipMemsetAsync(hist, 0, 204800, stream);
  hipMemsetAsync(flg, 0, 1024, stream);

  f2bf_kernel<<<12800, 256, 0, stream>>>(x, xbf, 13107200 / 4);
  f2bf_kernel<<<256,   256, 0, stream>>>(encW, ewbf, 262144 / 4);

  gru_recur<<<256, 320, GRU_LDS, stream>>>(xbf, Whh, Wih, bih, bhh, hist, flg);
  att_pool<<<1600, 512, ATT_LDS, stream>>>(hist, ewbf, encb, v);

  gemm_bt<<<dim3(16, 7), 256, 0, stream>>>(v, innW, hin, 100, 1024, 1024, nullptr, 0);
  gat_att<20><<<5, 256, 0, stream>>>(hin, innas, innad, innb, iemb);
  pool_att<<<20, 256, 0, stream>>>(v, poolW, poolb, catv);
  gemm_bt<<<dim3(16, 1), 256, 0, stream>>>(catv, catW, cath, 5, 1024, 1024, nullptr, 0);
  gat_att<5><<<1, 256, 0, stream>>>(cath, catas, catad, catb, cato);
  concat_kernel<<<1200, 256, 0, stream>>>(v, cato, iemb, fbuf);
  gemm_bt<<<dim3(16, 7), 256, 0, stream>>>(fbuf, fusW, fout, 100, 1024, 3072, fusb, 1);
  heads<<<25, 256, 0, stream>>>(fout, regW, regb, clsW, clsb, out);

  (void)in_sizes; (void)n_in; (void)out_size; (void)ws_size;
}

// Round 5
// 4219.368 us; speedup vs baseline: 1.4894x; 1.2180x over previous
//
#include <hip/hip_runtime.h>
#include <hip/hip_bf16.h>

// ============================================================================
// CategoricalGraphAtt on MI355X.
// R5 = R4 with the inline-asm operand fixed (ext_vector_type(4) int for the
// 128-bit store payload — HIP's int4 struct can't bind to a "v" constraint).
// GRU MALL-contention fixes: slice-major hist (WG's h' contiguous 800B, stored
// as 50x16B sc0sc1 dwordx4 by wave 4 via LDS repack), per-consumer-WG flag
// replication (1 poller/line), wave-4-private store+ack+flag tail, 2 LDS-only
// barriers/step.
// ============================================================================

typedef __bf16 bf16x8 __attribute__((ext_vector_type(8)));
typedef float  floatx4 __attribute__((ext_vector_type(4)));
typedef int    intx4  __attribute__((ext_vector_type(4)));

struct US8 { unsigned short u[8]; };

__device__ __forceinline__ unsigned short f2bf(float f) {
  unsigned u = __builtin_bit_cast(unsigned, f);
  u += 0x7fffu + ((u >> 16) & 1u);           // RNE
  return (unsigned short)(u >> 16);
}
__device__ __forceinline__ float bf2f(unsigned short h) {
  return __builtin_bit_cast(float, ((unsigned)h) << 16);
}
__device__ __forceinline__ float sigm(float x) { return 1.f / (1.f + __expf(-x)); }

// raw barrier: LDS-only ordering (no vmcnt drain)
__device__ __forceinline__ void bar_lds() {
  asm volatile("s_waitcnt lgkmcnt(0)" ::: "memory");
  __builtin_amdgcn_s_barrier();
  asm volatile("" ::: "memory");
}

// ---------------- workspace layout (bytes) ----------------
static const size_t OF_XBF   = 0;                 // bf16 x [100][512][256]   26,214,400
static const size_t OF_HIST  = 26214400;          // bf16 h_hist [513][256 slc][25 r][16 j] 105,062,400
static const size_t OF_ENCW  = 131277824;         // bf16 enc_att_W [512][512] 524,288
static const size_t OF_V     = 131802112;         // f32 v [100][1024]
static const size_t OF_HIN   = 132211712;         // f32 inner-GAT h
static const size_t OF_IEMB  = 132621312;         // f32 inner_emb
static const size_t OF_CATV  = 133030912;         // f32 cat_vec (pooled) [5][1024]
static const size_t OF_CATH  = 133051392;         // f32 cat-GAT h
static const size_t OF_CATO  = 133071872;         // f32 cat GAT out
static const size_t OF_FBUF  = 133092352;         // f32 fusion input [100][3072]
static const size_t OF_FOUT  = 134321152;         // f32 fusion output [100][1024]
static const size_t OF_FLAGS = 134730752;         // int flags[256 cwg][4 wave][16] = 65,536

// ---------------- fp32 -> bf16 convert ----------------
__global__ void f2bf_kernel(const float* __restrict__ src, unsigned short* __restrict__ dst, int n4) {
  int i = blockIdx.x * 256 + threadIdx.x;
  if (i < n4) {
    float4 v = ((const float4*)src)[i];
    ushort4 o;
    o.x = f2bf(v.x); o.y = f2bf(v.y); o.z = f2bf(v.z); o.w = f2bf(v.w);
    ((ushort4*)dst)[i] = o;
  }
}

// ---------------- persistent GRU recurrence ----------------
// grid 256 = 4 groups(25 rows) x 64 slices(16 j). block 320 (5 waves).
// waves 0-3: k-steps 8w..8w+8 of h-part (K=1024); wave 4: x-part (K=256) +
// the whole store/flag tail.
// hist layout per step: [slice sg(256)][row(25)][16 j] bf16 (400 shorts/slice).
// LDS: hbf_pack u32[200] @0 (overlays Bw after init) | Bw 122880 | bias @122880
//      | ghp [30][16col][20] f32 @123136 | hfp [16][25] f32 @161536.
#define GRU_LDS 163136
__global__ void __launch_bounds__(320) gru_recur(
    const unsigned short* __restrict__ xbf,
    const float* __restrict__ Whh, const float* __restrict__ Wih,
    const float* __restrict__ bih, const float* __restrict__ bhh,
    unsigned short* hist, int* flags)
{
  extern __shared__ char smem[];
  unsigned* hbf  = (unsigned*)smem;                  // [25 row][8] packed bf16 pairs
  unsigned short* Bw  = (unsigned short*)smem;       // init-only gather scratch
  float* biasl = (float*)(smem + 122880);            // [4][16]: r,z,hn,xn
  float* ghp   = (float*)(smem + 123136);            // [30 blk][16 col][20]
  float* hfp   = (float*)(smem + 161536);            // fp32 h state [16 l][25 b]

  const int tid  = threadIdx.x;
  const int lane = tid & 63;
  const int w    = tid >> 6;       // 0..4
  const int wg   = blockIdx.x;
  const int g    = wg >> 6;        // batch group 0..3
  const int s    = wg & 63;        // j slice 0..63
  const int gb   = g * 25;
  const int myq  = s >> 4;         // producer quarter

  // ---- gather B (Whh/Wih rows for this slice) into LDS in frag order ----
  for (int o = tid; o < 7680; o += 320) {
    int kk, ln; const float* sp; unsigned short* dst;
    if (o < 5120) {
      int q = o >= 2560; int rem = o - q * 2560;
      kk = rem >> 6; ln = rem & 63;
      int l = ln & 15, ksub = ln >> 4, j = s * 16 + l;
      int k = kk * 32 + ksub * 8;
      sp = (k < 1024) ? (Whh + (size_t)(q * 1024 + j) * 1024 + k)
                      : (Wih + (size_t)(q * 1024 + j) * 256 + (k - 1024));
      dst = Bw + ((size_t)((q * 40 + kk) * 64 + ln)) * 8;
    } else if (o < 7168) {
      int o2 = o - 5120; kk = o2 >> 6; ln = o2 & 63;
      int l = ln & 15, ksub = ln >> 4, j = s * 16 + l;
      sp = Whh + (size_t)(2048 + j) * 1024 + kk * 32 + ksub * 8;
      dst = Bw + (size_t)(5120 + kk * 64 + ln) * 8;
    } else {
      int o3 = o - 7168; kk = o3 >> 6; ln = o3 & 63;
      int l = ln & 15, ksub = ln >> 4, j = s * 16 + l;
      sp = Wih + (size_t)(2048 + j) * 256 + kk * 32 + ksub * 8;
      dst = Bw + (size_t)(7168 + kk * 64 + ln) * 8;
    }
    float4 f0 = *(const float4*)sp;
    float4 f1 = *(const float4*)(sp + 4);
    dst[0] = f2bf(f0.x); dst[1] = f2bf(f0.y); dst[2] = f2bf(f0.z); dst[3] = f2bf(f0.w);
    dst[4] = f2bf(f1.x); dst[5] = f2bf(f1.y); dst[6] = f2bf(f1.z); dst[7] = f2bf(f1.w);
  }
  if (tid < 16) {
    int j = s * 16 + tid;
    biasl[tid]      = bih[j]        + bhh[j];
    biasl[16 + tid] = bih[1024 + j] + bhh[1024 + j];
    biasl[32 + tid] = bhh[2048 + j];
    biasl[48 + tid] = bih[2048 + j];
  }
  for (int i = tid; i < 400; i += 320) hfp[i] = 0.f;
  __syncthreads();

  // ---- hoist B fragments (persist across all 512 steps) ----
  bf16x8 Breg[24];
  #pragma unroll
  for (int lk = 0; lk < 8; lk++) {
    int kk = w * 8 + lk;
    Breg[lk * 3 + 0] = __builtin_bit_cast(bf16x8, *(const intx4*)(Bw + (size_t)((kk)      * 64 + lane) * 8));
    Breg[lk * 3 + 1] = __builtin_bit_cast(bf16x8, *(const intx4*)(Bw + (size_t)((40 + kk) * 64 + lane) * 8));
    const unsigned short* np = (w < 4)
        ? (Bw + (size_t)(5120 + kk * 64 + lane) * 8)
        : (Bw + (size_t)(7168 + (kk - 32) * 64 + lane) * 8);
    Breg[lk * 3 + 2] = __builtin_bit_cast(bf16x8, *(const intx4*)np);
  }

  // A-operand addressing.
  // h (slice-major): sg = g*64 + 2*kk + (lane>>5); elem = sg*400 + row*16 + ((lane>>4)&1)*8
  // x (row-major): unchanged.
  const int kf_x = (lane >> 4) * 8;
  size_t baseA[2], rowx[2];
  #pragma unroll
  for (int mt = 0; mt < 2; mt++) {
    int m = mt * 16 + (lane & 15);
    int bb = (m < 25) ? m : 24;           // clamp pad rows
    baseA[mt] = (size_t)((g * 64 + (lane >> 5)) * 400 + bb * 16 + ((lane >> 4) & 1) * 8);
    rowx[mt]  = (size_t)(gb + bb) * 512 * 256;
  }

  const int* pollline = flags + (wg * 4 + w) * 16;       // private per (WG, wave)

  for (int t = 0; t < 512; t++) {
    // ---- wait for this wave's k-quarter producers (private line, no sleep) ----
    if (w < 4) {
      for (;;) {
        int f = __hip_atomic_load(pollline + (lane & 15), __ATOMIC_RELAXED, __HIP_MEMORY_SCOPE_AGENT);
        if (__all(f >= t)) break;
      }
      asm volatile("" ::: "memory");   // no hoisting of h loads above the spin
    }

    const unsigned short* hrow = hist + (size_t)t * 102400;
    floatx4 acc[2][3];
    #pragma unroll
    for (int mt = 0; mt < 2; mt++)
      #pragma unroll
      for (int gg = 0; gg < 3; gg++) acc[mt][gg] = floatx4{0.f, 0.f, 0.f, 0.f};

    #pragma unroll
    for (int lk = 0; lk < 8; lk++) {
      int kk = w * 8 + lk;
      #pragma unroll
      for (int mt = 0; mt < 2; mt++) {
        const unsigned short* ap = (w < 4)
            ? (hrow + baseA[mt] + (size_t)kk * 800)
            : (xbf + rowx[mt] + (size_t)t * 256 + (kk - 32) * 32 + kf_x);
        bf16x8 a = __builtin_bit_cast(bf16x8, *(const intx4*)ap);
        acc[mt][0] = __builtin_amdgcn_mfma_f32_16x16x32_bf16(a, Breg[lk * 3 + 0], acc[mt][0], 0, 0, 0);
        acc[mt][1] = __builtin_amdgcn_mfma_f32_16x16x32_bf16(a, Breg[lk * 3 + 1], acc[mt][1], 0, 0, 0);
        acc[mt][2] = __builtin_amdgcn_mfma_f32_16x16x32_bf16(a, Breg[lk * 3 + 2], acc[mt][2], 0, 0, 0);
      }
    }

    // partials -> LDS: [block][col l][20] with rows contiguous (float4 at q*4)
    {
      int base = (lane & 15) * 20 + (lane >> 4) * 4;
      #pragma unroll
      for (int mt = 0; mt < 2; mt++)
        #pragma unroll
        for (int gg = 0; gg < 3; gg++)
          *(floatx4*)(ghp + (size_t)((w * 2 + mt) * 3 + gg) * 320 + base) = acc[mt][gg];
    }
    bar_lds();   // (1) partials visible

    // ---- epilogue: waves 0-3, thread (lp = col-pair, b = row) ----
    if (tid < 256) {
      int lp = tid >> 5, b = tid & 31;
      if (b < 25) {
        int mt2 = b >> 4, rr = b & 15;
        unsigned packed = 0;
        #pragma unroll
        for (int ii = 0; ii < 2; ii++) {
          int l = lp * 2 + ii;
          int off = l * 20 + rr;
          float ghr = 0.f, ghz = 0.f, ghnh = 0.f, ghnx;
          #pragma unroll
          for (int ww = 0; ww < 4; ww++) {
            const float* gq = ghp + (size_t)((ww * 2 + mt2) * 3) * 320 + off;
            ghr += gq[0]; ghz += gq[320]; ghnh += gq[640];
          }
          { const float* gq = ghp + (size_t)((4 * 2 + mt2) * 3) * 320 + off;
            ghr += gq[0]; ghz += gq[320]; ghnx = gq[640]; }
          float r = sigm(ghr + biasl[l]);
          float z = sigm(ghz + biasl[16 + l]);
          float nv = ghnx + biasl[48 + l] + r * (ghnh + biasl[32 + l]);
          nv = fminf(fmaxf(nv, -15.f), 15.f);
          float e2 = __expf(-2.f * nv);
          float n = (1.f - e2) / (1.f + e2);
          float ho = hfp[l * 25 + b];
          float hn = (1.f - z) * n + z * ho;
          hfp[l * 25 + b] = hn;
          packed |= ((unsigned)f2bf(hn)) << (16 * ii);
        }
        hbf[b * 8 + lp] = packed;          // stage for wave-4 packed store
      }
    }
    bar_lds();   // (2) hbf visible to wave 4; ghp free for next MFMA round

    // ---- wave 4: contiguous 16B write-through stores + ack + flag fan-out ----
    if (w == 4) {
      if (lane < 50) {
        int b = lane >> 1, hs = lane & 1;
        intx4 d = *(const intx4*)&hbf[b * 8 + hs * 4];
        unsigned long long addr = (unsigned long long)(hist + (size_t)(t + 1) * 102400
                                  + (size_t)((g * 64 + s) * 400 + b * 16 + hs * 8));
        asm volatile("global_store_dwordx4 %0, %1, off sc0 sc1" :: "v"(addr), "v"(d) : "memory");
      }
      if (t < 511) {
        asm volatile("s_waitcnt vmcnt(0)" ::: "memory");   // h' at MALL before flags
        __hip_atomic_store(flags + ((g * 64 + lane) * 4 + myq) * 16 + (s & 15), t + 1,
                           __ATOMIC_RELAXED, __HIP_MEMORY_SCOPE_AGENT);
      }
    }
    // waves 0-3 fall through to the next poll immediately.
  }
}

// ---------------- fused time attention ----------------
// grid 1600 (one 64-col block of n'=(b*1024+d)), block 512 (8 waves).
#define ATT_LDS 68096
__global__ void __launch_bounds__(512) att_pool(
    const unsigned short* __restrict__ hist,   // slots 1..512, slice-major
    const unsigned short* __restrict__ encw,   // bf16 [512][512]
    const float* __restrict__ encb,
    float* __restrict__ vout)
{
  extern __shared__ char smem[];
  unsigned short* Bs = (unsigned short*)smem;          // [16ks][4nt][64lane][8]
  float* red  = (float*)(smem + 65536);                // [8][64]
  float* cmax = (float*)(smem + 65536 + 2048);
  float* csum = (float*)(smem + 65536 + 2048 + 256);

  const int tid = threadIdx.x, w = tid >> 6, lane = tid & 63;
  const int q = lane >> 4, col = lane & 15;
  const int n0 = blockIdx.x * 64;
  const int bg = n0 >> 10, d0 = n0 & 1023;
  const int gA = bg / 25, rA = bg - gA * 25;

  // stage hs tile (slice-major gather, transposed scatter into frag layout)
  for (int ii = 0; ii < 8; ii++) {
    int c = tid + 512 * ii;
    int t = c >> 3, dd = c & 7;
    int sA = (d0 >> 4) + (dd >> 1), hsA = dd & 1;
    intx4 li = *(const intx4*)(hist + (size_t)(t + 1) * 102400
                             + (size_t)((gA * 64 + sA) * 400 + rA * 16 + hsA * 8));
    US8 u8 = __builtin_bit_cast(US8, li);
    int kstep = t >> 5, ksub = (t >> 3) & 3, i = t & 7;
    int ntile = dd >> 1, nc0 = (dd & 1) * 8;
    unsigned short* dst = Bs + ((size_t)((kstep * 4 + ntile) * 64 + ksub * 16 + nc0)) * 8 + i;
    #pragma unroll
    for (int jj = 0; jj < 8; jj++) dst[jj * 8] = u8.u[jj];
  }
  __syncthreads();

  floatx4 acc[4][4];
  #pragma unroll
  for (int mi = 0; mi < 4; mi++)
    #pragma unroll
    for (int ni = 0; ni < 4; ni++) acc[mi][ni] = floatx4{0.f, 0.f, 0.f, 0.f};

  #pragma unroll 2
  for (int kk = 0; kk < 16; kk++) {
    int tch = kk * 32 + q * 8;
    bf16x8 af[4];
    #pragma unroll
    for (int mi = 0; mi < 4; mi++) {
      int u = (w * 4 + mi) * 16 + col;
      af[mi] = __builtin_bit_cast(bf16x8, *(const intx4*)(encw + (size_t)u * 512 + tch));
    }
    #pragma unroll
    for (int ni = 0; ni < 4; ni++) {
      bf16x8 bf = __builtin_bit_cast(bf16x8, *(const intx4*)(Bs + (size_t)((kk * 4 + ni) * 64 + lane) * 8));
      #pragma unroll
      for (int mi = 0; mi < 4; mi++)
        acc[mi][ni] = __builtin_amdgcn_mfma_f32_16x16x32_bf16(af[mi], bf, acc[mi][ni], 0, 0, 0);
    }
  }

  // + row bias
  #pragma unroll
  for (int mi = 0; mi < 4; mi++) {
    int ub = (w * 4 + mi) * 16 + q * 4;
    float b0 = encb[ub], b1 = encb[ub + 1], b2 = encb[ub + 2], b3 = encb[ub + 3];
    #pragma unroll
    for (int ni = 0; ni < 4; ni++) {
      acc[mi][ni][0] += b0; acc[mi][ni][1] += b1; acc[mi][ni][2] += b2; acc[mi][ni][3] += b3;
    }
  }
  // column max
  #pragma unroll
  for (int ni = 0; ni < 4; ni++) {
    float m = -1e30f;
    #pragma unroll
    for (int mi = 0; mi < 4; mi++)
      #pragma unroll
      for (int r = 0; r < 4; r++) m = fmaxf(m, acc[mi][ni][r]);
    m = fmaxf(m, __shfl_xor(m, 16)); m = fmaxf(m, __shfl_xor(m, 32));
    red[w * 64 + ni * 16 + col] = m;
  }
  __syncthreads();
  if (tid < 64) {
    float m = red[tid];
    for (int w2 = 1; w2 < 8; w2++) m = fmaxf(m, red[w2 * 64 + tid]);
    cmax[tid] = m;
  }
  __syncthreads();
  // exp + column sum
  #pragma unroll
  for (int ni = 0; ni < 4; ni++) {
    float cm = cmax[ni * 16 + col];
    float sum = 0.f;
    #pragma unroll
    for (int mi = 0; mi < 4; mi++)
      #pragma unroll
      for (int r = 0; r < 4; r++) {
        float e = __expf(acc[mi][ni][r] - cm);
        acc[mi][ni][r] = e; sum += e;
      }
    sum += __shfl_xor(sum, 16); sum += __shfl_xor(sum, 32);
    red[w * 64 + ni * 16 + col] = sum;
  }
  __syncthreads();
  if (tid < 64) {
    float sm = 0.f;
    for (int w2 = 0; w2 < 8; w2++) sm += red[w2 * 64 + tid];
    csum[tid] = sm;
  }
  __syncthreads();
  // weighted sum of hs
  #pragma unroll
  for (int ni = 0; ni < 4; ni++) {
    float p = 0.f;
    #pragma unroll
    for (int mi = 0; mi < 4; mi++) {
      int u0 = (w * 4 + mi) * 16 + q * 4;
      int ks = u0 >> 5, ksb = (u0 >> 3) & 3, i0 = u0 & 7;
      const unsigned short* hp = Bs + (size_t)((ks * 4 + ni) * 64 + ksb * 16 + col) * 8 + i0;
      p += acc[mi][ni][0] * bf2f(hp[0]) + acc[mi][ni][1] * bf2f(hp[1])
         + acc[mi][ni][2] * bf2f(hp[2]) + acc[mi][ni][3] * bf2f(hp[3]);
    }
    p += __shfl_xor(p, 16); p += __shfl_xor(p, 32);
    red[w * 64 + ni * 16 + col] = p;
  }
  __syncthreads();
  if (tid < 64) {
    float p = 0.f;
    for (int w2 = 0; w2 < 8; w2++) p += red[w2 * 64 + tid];
    vout[n0 + tid] = p / csum[tid];
  }
}

// ---------------- small fp32 GEMM: C(M,N) = A(M,K) @ B(N,K)^T [+bias][+relu] ----------------
__global__ void gemm_bt(const float* __restrict__ A, const float* __restrict__ B,
                        float* __restrict__ C, int M, int N, int K,
                        const float* __restrict__ bias, int relu)
{
  __shared__ float Al[16][33];
  __shared__ float Bl[64][33];
  int tx = threadIdx.x;
  int nb = blockIdx.x, mb = blockIdx.y;
  int n = nb * 64 + (tx & 63);
  int mq = tx >> 6;
  float acc[4] = {0.f, 0.f, 0.f, 0.f};
  for (int k0 = 0; k0 < K; k0 += 32) {
    for (int e = tx; e < 512; e += 256) {
      int r = e >> 5, c = e & 31; int m = mb * 16 + r;
      Al[r][c] = (m < M) ? A[(size_t)m * K + k0 + c] : 0.f;
    }
    for (int e = tx; e < 2048; e += 256) {
      int r = e >> 5, c = e & 31;
      Bl[r][c] = B[(size_t)(nb * 64 + r) * K + k0 + c];
    }
    __syncthreads();
    int nn = tx & 63;
    #pragma unroll 8
    for (int c = 0; c < 32; c++) {
      float bv = Bl[nn][c];
      #pragma unroll
      for (int i = 0; i < 4; i++) acc[i] += Al[mq * 4 + i][c] * bv;
    }
    __syncthreads();
  }
  #pragma unroll
  for (int i = 0; i < 4; i++) {
    int m = mb * 16 + mq * 4 + i;
    if (m < M && n < N) {
      float r = acc[i] + (bias ? bias[n] : 0.f);
      if (relu) r = fmaxf(r, 0.f);
      C[(size_t)m * N + n] = r;
    }
  }
}

// ---------------- GAT attention (complete graph + self loops within each block of NN nodes) ----------------
template <int NN>
__global__ void gat_att(const float* __restrict__ h, const float* __restrict__ asrc,
                        const float* __restrict__ adst, const float* __restrict__ bias,
                        float* __restrict__ out)
{
  __shared__ float asd[2][NN];
  __shared__ float P[NN][NN];
  int c = blockIdx.x, tx = threadIdx.x;
  int wid = tx >> 6, lane = tx & 63;
  for (int idx = wid; idx < 2 * NN; idx += 4) {
    int which = idx >= NN; int j = which ? idx - NN : idx;
    const float* av = which ? adst : asrc;
    float p = 0.f;
    for (int k = lane; k < 1024; k += 64) p += h[(size_t)(c * NN + j) * 1024 + k] * av[k];
    for (int m = 32; m; m >>= 1) p += __shfl_xor(p, m);
    if (lane == 0) asd[which][j] = p;
  }
  __syncthreads();
  if (tx < NN) {
    int i = tx; float mx = -1e30f; float e[NN];
    #pragma unroll
    for (int j = 0; j < NN; j++) {
      float x = asd[0][j] + asd[1][i];
      x = (x < 0.f) ? 0.2f * x : x;
      e[j] = x; mx = fmaxf(mx, x);
    }
    float s = 0.f;
    #pragma unroll
    for (int j = 0; j < NN; j++) { e[j] = __expf(e[j] - mx); s += e[j]; }
    #pragma unroll
    for (int j = 0; j < NN; j++) P[i][j] = e[j] / s;
  }
  __syncthreads();
  for (int ee = tx; ee < NN * 1024; ee += 256) {
    int i = ee >> 10, d = ee & 1023;
    float s = 0.f;
    #pragma unroll
    for (int j = 0; j < NN; j++) s += P[i][j] * h[(size_t)(c * NN + j) * 1024 + d];
    out[(size_t)(c * NN + i) * 1024 + d] = s + bias[d];
  }
}

// ---------------- stock->category pooling attention ----------------
__global__ void pool_att(const float* __restrict__ v, const float* __restrict__ pW,
                         const float* __restrict__ pb, float* __restrict__ catv)
{
  __shared__ float W[400]; __shared__ float bsh[20];
  int tx = threadIdx.x;
  for (int i = tx; i < 400; i += 256) W[i] = pW[i];
  if (tx < 20) bsh[tx] = pb[tx];
  __syncthreads();
  int gid = blockIdx.x * 256 + tx;
  int c = gid >> 10, d = gid & 1023;
  float vals[20];
  #pragma unroll
  for (int t = 0; t < 20; t++) vals[t] = v[(size_t)(c * 20 + t) * 1024 + d];
  float wv[20]; float mx = -1e30f;
  #pragma unroll
  for (int u = 0; u < 20; u++) {
    float s = bsh[u];
    #pragma unroll
    for (int t = 0; t < 20; t++) s += vals[t] * W[u * 20 + t];
    wv[u] = s; mx = fmaxf(mx, s);
  }
  float sum = 0.f, out = 0.f;
  #pragma unroll
  for (int u = 0; u < 20; u++) { float e = __expf(wv[u] - mx); sum += e; out += e * vals[u]; }
  catv[gid] = out / sum;
}

// ---------------- fusion concat ----------------
__global__ void concat_kernel(const float* __restrict__ v, const float* __restrict__ cato,
                              const float* __restrict__ iemb, float* __restrict__ F)
{
  int gid = blockIdx.x * 256 + threadIdx.x;
  if (gid < 307200) {
    int i = gid / 3072;
    int k = gid - i * 3072;
    float r;
    if (k < 1024)       r = v[(size_t)i * 1024 + k];
    else if (k < 2048)  r = cato[(size_t)(i / 20) * 1024 + (k - 1024)];
    else                r = iemb[(size_t)i * 1024 + (k - 2048)];
    F[gid] = r;
  }
}

// ---------------- output heads ----------------
__global__ void heads(const float* __restrict__ f, const float* __restrict__ rw,
                      const float* __restrict__ rb, const float* __restrict__ cw,
                      const float* __restrict__ cb, float* __restrict__ out)
{
  int b = blockIdx.x * 4 + (threadIdx.x >> 6);
  int lane = threadIdx.x & 63;
  float pr = 0.f, pc = 0.f;
  for (int k = lane; k < 1024; k += 64) {
    float x = f[(size_t)b * 1024 + k];
    pr += x * rw[k]; pc += x * cw[k];
  }
  for (int m = 32; m; m >>= 1) { pr += __shfl_xor(pr, m); pc += __shfl_xor(pc, m); }
  if (lane == 0) {
    out[b] = pr + rb[0];
    out[100 + b] = sigm(pc + cb[0]);
  }
}

// ============================================================================
extern "C" void kernel_launch(void* const* d_in, const int* in_sizes, int n_in,
                              void* d_out, int out_size, void* d_ws, size_t ws_size,
                              hipStream_t stream)
{
  const float* x     = (const float*)d_in[0];
  const float* Wih   = (const float*)d_in[1];
  const float* Whh   = (const float*)d_in[2];
  const float* bih   = (const float*)d_in[3];
  const float* bhh   = (const float*)d_in[4];
  const float* encW  = (const float*)d_in[5];
  const float* encb  = (const float*)d_in[6];
  const float* poolW = (const float*)d_in[7];
  const float* poolb = (const float*)d_in[8];
  const float* innW  = (const float*)d_in[9];
  const float* innas = (const float*)d_in[10];
  const float* innad = (const float*)d_in[11];
  const float* innb  = (const float*)d_in[12];
  const float* catW  = (const float*)d_in[13];
  const float* catas = (const float*)d_in[14];
  const float* catad = (const float*)d_in[15];
  const float* catb  = (const float*)d_in[16];
  const float* fusW  = (const float*)d_in[17];
  const float* fusb  = (const float*)d_in[18];
  const float* regW  = (const float*)d_in[19];
  const float* regb  = (const float*)d_in[20];
  const float* clsW  = (const float*)d_in[21];
  const float* clsb  = (const float*)d_in[22];
  float* out = (float*)d_out;
  char* ws = (char*)d_ws;

  unsigned short* xbf  = (unsigned short*)(ws + OF_XBF);
  unsigned short* hist = (unsigned short*)(ws + OF_HIST);
  int*            flg  = (int*)(ws + OF_FLAGS);
  unsigned short* ewbf = (unsigned short*)(ws + OF_ENCW);
  float* v    = (float*)(ws + OF_V);
  float* hin  = (float*)(ws + OF_HIN);
  float* iemb = (float*)(ws + OF_IEMB);
  float* catv = (float*)(ws + OF_CATV);
  float* cath = (float*)(ws + OF_CATH);
  float* cato = (float*)(ws + OF_CATO);
  float* fbuf = (float*)(ws + OF_FBUF);
  float* fout = (float*)(ws + OF_FOUT);

  (void)hipFuncSetAttribute((const void*)gru_recur, hipFuncAttributeMaxDynamicSharedMemorySize, GRU_LDS);
  (void)hipFuncSetAttribute((const void*)att_pool,  hipFuncAttributeMaxDynamicSharedMemorySize, ATT_LDS);

  // h(0) = 0 (slot 0) and flag reset — stream-ordered, visible at kernel dispatch
  (void)hipMemsetAsync(hist, 0, 204800, stream);
  (void)hipMemsetAsync(flg, 0, 65536, stream);

  f2bf_kernel<<<12800, 256, 0, stream>>>(x, xbf, 13107200 / 4);
  f2bf_kernel<<<256,   256, 0, stream>>>(encW, ewbf, 262144 / 4);

  gru_recur<<<256, 320, GRU_LDS, stream>>>(xbf, Whh, Wih, bih, bhh, hist, flg);
  att_pool<<<1600, 512, ATT_LDS, stream>>>(hist, ewbf, encb, v);

  gemm_bt<<<dim3(16, 7), 256, 0, stream>>>(v, innW, hin, 100, 1024, 1024, nullptr, 0);
  gat_att<20><<<5, 256, 0, stream>>>(hin, innas, innad, innb, iemb);
  pool_att<<<20, 256, 0, stream>>>(v, poolW, poolb, catv);
  gemm_bt<<<dim3(16, 1), 256, 0, stream>>>(catv, catW, cath, 5, 1024, 1024, nullptr, 0);
  gat_att<5><<<1, 256, 0, stream>>>(cath, catas, catad, catb, cato);
  concat_kernel<<<1200, 256, 0, stream>>>(v, cato, iemb, fbuf);
  gemm_bt<<<dim3(16, 7), 256, 0, stream>>>(fbuf, fusW, fout, 100, 1024, 3072, fusb, 1);
  heads<<<25, 256, 0, stream>>>(fout, regW, regb, clsW, clsb, out);

  (void)in_sizes; (void)n_in; (void)out_size; (void)ws_size;
}